// Round 1
// 164.626 us; speedup vs baseline: 1.0348x; 1.0348x over previous
//
#include <hip/hip_runtime.h>
#include <math.h>

#define B_  16
#define L_  4096
#define D_  64
#define R_  4
#define NB_ 64
#define BL_ 64
#define FIXCAP 8192

typedef _Float16 f16x8 __attribute__((ext_vector_type(8)));
typedef _Float16 f16x2 __attribute__((ext_vector_type(2)));
typedef float    f32x4 __attribute__((ext_vector_type(4)));

// ---------------- ws layout ----------------
// [0MB,1MB)     rmn    double   [B][R][32][64]
// [1MB,2MB)     h      int      [B][R][L]
// [2MB,3MB)     hi     int      (unused now)
// [3MB,4MB)     oi     int      [B][R][L]
// [4MB,5MB)     lse    float    [B][R][L]   (original index)
// [5MB,+256)    rwmax float[64]; [+256,+512) rwsum; [+512] fix_cnt; [+1024,) fix_list
// [6MB,40MB)    attn   _Float16 [B][R][L][64]  (original index)
// [40MB,+256K)  rhi    _Float16 [B][128][64]
// [40.5MB,+256K)rlo    _Float16 [B][128][64]
// [41MB,45MB)   meta   int4     [B*R][L]
// [45MB,53MB)   qhf    _Float16 [B][L][64]   raw q, f16
// [53MB,61MB)   khf    _Float16 [B][L][64]   q/||q|| * log2e/8, f16   (log2 domain!)
// [61MB,69MB)   vhf    _Float16 [B][L][64]   v, f16

// K0: normalize rand_matrix along d, store fp64 + split-f16 copies; zero fix_cnt.
__global__ __launch_bounds__(64) void k_rmnorm(const float* __restrict__ rm,
                                               double* __restrict__ rmn,
                                               _Float16* __restrict__ rhi_g,
                                               _Float16* __restrict__ rlo_g,
                                               int* __restrict__ fix_cnt) {
    if (blockIdx.x == 0 && threadIdx.x == 0) *fix_cnt = 0;
    int blk = blockIdx.x;                 // b*128 + r*32 + n
    int b = blk >> 7, r = (blk >> 5) & 3, n = blk & 31;
    int d = threadIdx.x;
    double v = (double)rm[(((size_t)b * 64 + d) * 4 + r) * 32 + n];
    double sq = v * v;
    #pragma unroll
    for (int off = 32; off > 0; off >>= 1) sq += __shfl_down(sq, off);
    double tot = __shfl(sq, 0);
    double nv = v / sqrt(tot);
    rmn[(((size_t)b * 4 + r) * 32 + n) * 64 + d] = nv;
    float f = (float)nv;
    _Float16 hi = (_Float16)f;
    size_t gi = ((size_t)b * 128 + r * 32 + n) * 64 + d;
    rhi_g[gi] = hi;
    rlo_g[gi] = (_Float16)(f - (float)hi);
}

// K1: split-f16 MFMA hash + f16 tensor prep (qhf/khf/vhf); deferred exact fix list.
__global__ __launch_bounds__(256, 4) void k_hash(const float* __restrict__ q,
                                                 const float* __restrict__ value,
                                                 const _Float16* __restrict__ rhi_g,
                                                 const _Float16* __restrict__ rlo_g,
                                                 int* __restrict__ h_ws,
                                                 int* __restrict__ fix_cnt,
                                                 int* __restrict__ fix_list,
                                                 _Float16* __restrict__ qhf,
                                                 _Float16* __restrict__ khf,
                                                 _Float16* __restrict__ vhf) {
    __shared__ __align__(16) char smem[36864];
    _Float16* Rhi = (_Float16*)smem;            // [128][72]
    _Float16* Rlo = (_Float16*)(smem + 18432);  // [128][72]
    float*    Sc  = (float*)smem;               // overlay [64][133]

    int blk = blockIdx.x;                 // b*64 + chunk
    int b = blk >> 6, chunk = blk & 63;
    int tid = threadIdx.x;
    int w = tid >> 6, lane = tid & 63, quad = lane >> 4, l15 = lane & 15;

    {   // vhf prep: 64 rows of v -> f16 (streaming, no LDS)
        int row = chunk * 64 + (tid >> 2), sub = tid & 3;
        const float4* vp = (const float4*)(value + ((size_t)(b * L_ + row)) * 64 + sub * 16);
        f16x8 h0, h1;
        #pragma unroll
        for (int c = 0; c < 2; c++) {
            float4 t0 = vp[2 * c], t1 = vp[2 * c + 1];
            f16x8& hd = c ? h1 : h0;
            hd[0]=(_Float16)t0.x; hd[1]=(_Float16)t0.y; hd[2]=(_Float16)t0.z; hd[3]=(_Float16)t0.w;
            hd[4]=(_Float16)t1.x; hd[5]=(_Float16)t1.y; hd[6]=(_Float16)t1.z; hd[7]=(_Float16)t1.w;
        }
        _Float16* dst = vhf + ((size_t)(b * L_ + row)) * 64 + sub * 16;
        *(f16x8*)dst = h0;
        *(f16x8*)(dst + 8) = h1;
    }

    {   // stage R split halves
        int row = tid >> 1, dh = (tid & 1) * 32;
        const _Float16* sh = rhi_g + ((size_t)b * 128 + row) * 64 + dh;
        const _Float16* sl = rlo_g + ((size_t)b * 128 + row) * 64 + dh;
        #pragma unroll
        for (int g = 0; g < 4; g++) {
            *(f16x8*)&Rhi[row * 72 + dh + g * 8] = *(const f16x8*)(sh + g * 8);
            *(f16x8*)&Rlo[row * 72 + dh + g * 8] = *(const f16x8*)(sl + g * 8);
        }
    }

    int qrow = chunk * 64 + w * 16 + l15;
    const float* qp = q + ((size_t)(b * L_ + qrow)) * 64;
    float qv[16];
    #pragma unroll
    for (int kt = 0; kt < 2; kt++) {
        float4 t0 = *(const float4*)(qp + kt * 32 + quad * 8);
        float4 t1 = *(const float4*)(qp + kt * 32 + quad * 8 + 4);
        qv[8*kt+0]=t0.x; qv[8*kt+1]=t0.y; qv[8*kt+2]=t0.z; qv[8*kt+3]=t0.w;
        qv[8*kt+4]=t1.x; qv[8*kt+5]=t1.y; qv[8*kt+6]=t1.z; qv[8*kt+7]=t1.w;
    }
    f16x8 Ahi[2], Alo[2];
    #pragma unroll
    for (int kt = 0; kt < 2; kt++) {
        #pragma unroll
        for (int j = 0; j < 8; j++) {
            _Float16 hi = (_Float16)qv[8*kt+j];
            Ahi[kt][j] = hi;
            Alo[kt][j] = (_Float16)(qv[8*kt+j] - (float)hi);
        }
    }
    {   // qhf (raw f16) + khf (scaled f16, includes log2e for exp2-domain softmax)
        float ss = 0.f;
        #pragma unroll
        for (int j = 0; j < 16; j++) ss += qv[j] * qv[j];
        ss += __shfl_xor(ss, 16);
        ss += __shfl_xor(ss, 32);
        float nr = sqrtf(ss); if (nr < 1e-12f) nr = 1e-12f;
        float kscale = 0.18033688f / nr;   // 0.125 * log2(e)
        _Float16* qd = qhf + ((size_t)(b * L_ + qrow)) * 64;
        _Float16* kd = khf + ((size_t)(b * L_ + qrow)) * 64;
        #pragma unroll
        for (int kt = 0; kt < 2; kt++) {
            *(f16x8*)(qd + kt * 32 + quad * 8) = Ahi[kt];
            f16x8 hv;
            #pragma unroll
            for (int j = 0; j < 8; j++) hv[j] = (_Float16)(qv[8*kt+j] * kscale);
            *(f16x8*)(kd + kt * 32 + quad * 8) = hv;
        }
    }
    __syncthreads();

    f32x4 acc[8];
    #pragma unroll
    for (int jt = 0; jt < 8; jt++) acc[jt] = (f32x4){0.f, 0.f, 0.f, 0.f};
    #pragma unroll
    for (int jt = 0; jt < 8; jt++) {
        #pragma unroll
        for (int kt = 0; kt < 2; kt++) {
            f16x8 bh = *(const f16x8*)&Rhi[(jt * 16 + l15) * 72 + kt * 32 + quad * 8];
            f16x8 bl = *(const f16x8*)&Rlo[(jt * 16 + l15) * 72 + kt * 32 + quad * 8];
            acc[jt] = __builtin_amdgcn_mfma_f32_16x16x32_f16(Ahi[kt], bh, acc[jt], 0, 0, 0);
            acc[jt] = __builtin_amdgcn_mfma_f32_16x16x32_f16(Ahi[kt], bl, acc[jt], 0, 0, 0);
            acc[jt] = __builtin_amdgcn_mfma_f32_16x16x32_f16(Alo[kt], bh, acc[jt], 0, 0, 0);
        }
    }
    __syncthreads();

    #pragma unroll
    for (int jt = 0; jt < 8; jt++) {
        #pragma unroll
        for (int reg = 0; reg < 4; reg++)
            Sc[(w * 16 + quad * 4 + reg) * 133 + jt * 16 + l15] = acc[jt][reg];
    }
    __syncthreads();

    {
        // top-2 of |v| with sign-tagged argmax. Exact ties (|v| equal) always
        // satisfy v1-v2 < 4e-5 -> resolved by k_fix with reference tie order.
        int row = tid & 63, r = tid >> 6;
        const float* sp = &Sc[row * 133 + r * 32];
        float v1 = -1e30f, v2 = -1e30f; int i1 = 0;
        #pragma unroll
        for (int n = 0; n < 32; n++) {
            float v = sp[n];
            float a = fabsf(v);
            int cand = n | ((__float_as_uint(v) >> 26) & 32);
            if (a > v1) i1 = cand;
            v2 = __builtin_amdgcn_fmed3f(a, v1, v2);
            v1 = fmaxf(a, v1);
        }
        int l = chunk * 64 + row;
        h_ws[((size_t)(b * 4 + r)) * L_ + l] = i1;
        if (v1 - v2 < 4e-5f) {
            int slot = atomicAdd(fix_cnt, 1);
            if (slot < FIXCAP) fix_list[slot] = (b << 14) | (r << 12) | l;
        }
    }
}

// K1b: exact fp64 resolve, one wave per flagged row.
__global__ __launch_bounds__(64) void k_fix(const float* __restrict__ q,
                                            const double* __restrict__ rmn,
                                            const int* __restrict__ fix_cnt,
                                            const int* __restrict__ fix_list,
                                            int* __restrict__ h_ws) {
    int cnt = *fix_cnt; if (cnt > FIXCAP) cnt = FIXCAP;
    int lane = threadIdx.x;
    for (int i = blockIdx.x; i < cnt; i += gridDim.x) {
        int e = fix_list[i];
        int b = e >> 14, r = (e >> 12) & 3, l = e & 4095;
        int n = lane & 31;
        const double* rp = rmn + ((size_t)(b * 4 + r)) * 2048 + n * 64;
        const float* qr = q + ((size_t)(b * L_ + l)) * 64;
        double a0 = 0.0, a1 = 0.0, a2 = 0.0, a3 = 0.0;
        #pragma unroll
        for (int d = 0; d < 64; d += 4) {
            a0 += (double)qr[d]   * rp[d];
            a1 += (double)qr[d+1] * rp[d+1];
            a2 += (double)qr[d+2] * rp[d+2];
            a3 += (double)qr[d+3] * rp[d+3];
        }
        double acc = ((a0 + a1) + (a2 + a3));
        double v = (lane < 32) ? acc : -acc;
        int idx = lane;
        #pragma unroll
        for (int off = 1; off < 64; off <<= 1) {
            double ov = __shfl_xor(v, off);
            int   oidx = __shfl_xor(idx, off);
            if (ov > v || (ov == v && oidx < idx)) { v = ov; idx = oidx; }
        }
        if (lane == 0) h_ws[((size_t)(b * 4 + r)) * L_ + l] = idx;
    }
}

// K2: stable counting sort per (b,r) — 256 threads, keys in registers,
// per-thread-column histogram, hierarchical scan, LDS-staged coalesced oi.
__global__ __launch_bounds__(256) void k_sort(const int* __restrict__ h_ws,
                                              int* __restrict__ oi_ws) {
    __shared__ __align__(16) unsigned short cnt[64 * 257];   // [bucket][thread], stride 257
    __shared__ __align__(16) unsigned short oi_s[256 * 17];  // padded [t][k] staging
    __shared__ int part[256];                                // [seg][bucket] bases

    int br = blockIdx.x;
    int t = threadIdx.x;
    const int* hp = h_ws + (size_t)br * L_;

    // zero histogram (16448 u16 = 8224 u32)
    unsigned int* cz = (unsigned int*)cnt;
    #pragma unroll
    for (int i = 0; i < 33; i++) {
        int idx = i * 256 + t;
        if (idx < 8224) cz[idx] = 0;
    }

    // load 16 keys into registers (coalesced int4)
    int key[16];
    const int4* hp4 = (const int4*)(hp + t * 16);
    #pragma unroll
    for (int g = 0; g < 4; g++) {
        int4 v = hp4[g];
        key[g*4+0] = v.x; key[g*4+1] = v.y; key[g*4+2] = v.z; key[g*4+3] = v.w;
    }
    __syncthreads();

    // per-thread histogram
    #pragma unroll
    for (int k = 0; k < 16; k++) {
        unsigned short* c = &cnt[key[k] * 257 + t];
        *c = (unsigned short)(*c + 1);
    }
    __syncthreads();

    // within-segment exclusive prefix: thread (u = t&63, s = t>>6) walks its
    // segment's 64 thread-columns of bucket u.
    int u = t & 63, s = t >> 6;
    {
        int run = 0;
        int base_idx = u * 257 + s * 64;
        #pragma unroll 16
        for (int i = 0; i < 64; i++) {
            int c = cnt[base_idx + i];
            cnt[base_idx + i] = (unsigned short)run;
            run += c;
        }
        part[s * 64 + u] = run;
    }
    __syncthreads();

    // wave 0: cross-segment and cross-bucket exclusive bases
    if (t < 64) {
        int p0 = part[t], p1 = part[64 + t], p2 = part[128 + t], p3 = part[192 + t];
        int tot = p0 + p1 + p2 + p3;
        int v = tot;
        #pragma unroll
        for (int off = 1; off < 64; off <<= 1) {
            int o = __shfl_up(v, off);
            if (t >= off) v += o;
        }
        int base = v - tot;              // exclusive over buckets
        part[t]       = base;
        part[64 + t]  = base + p0;
        part[128 + t] = base + p0 + p1;
        part[192 + t] = base + p0 + p1 + p2;
    }
    __syncthreads();

    // scatter: pos = bucket/segment base + within-segment offset (stable)
    int sbase = s * 64;
    #pragma unroll
    for (int k = 0; k < 16; k++) {
        int uk = key[k];
        unsigned short* c = &cnt[uk * 257 + t];
        int pos = part[sbase + uk] + *c;
        *c = (unsigned short)(*c + 1);
        int idx = t * 16 + k;
        oi_s[(idx >> 4) * 17 + (idx & 15)] = (unsigned short)pos;
    }
    __syncthreads();

    // coalesced output
    int* op = oi_ws + (size_t)br * L_;
    #pragma unroll
    for (int k = 0; k < 16; k++) {
        int e = k * 256 + t;
        op[e] = (int)oi_s[(e >> 4) * 17 + (e & 15)];
    }
}

// K2b: per sorted position meta record — iterate over ORIGINAL index p so all
// reads are coalesced; single scattered int4 store.
__global__ __launch_bounds__(256) void k_meta(const int* __restrict__ h_ws,
                                              const int* __restrict__ oi_ws,
                                              int4* __restrict__ meta_ws) {
    int gid = blockIdx.x * 256 + threadIdx.x;
    int br = gid >> 12, p = gid & 4095;
    int b = br >> 2, rme = br & 3;
    int hh = h_ws[(size_t)br * L_ + p];
    int pack = 0, packm1 = 0, mypos = 0;
    #pragma unroll
    for (int r2 = 0; r2 < 4; r2++) {
        int o = oi_ws[((size_t)(b * 4 + r2)) * L_ + p];
        if (r2 == rme) mypos = o;
        int bk = o >> 6;
        pack   |= bk << (8 * r2);
        packm1 |= ((bk + 63) & 63) << (8 * r2);
    }
    meta_ws[(size_t)br * L_ + mypos] = make_int4(hh, p, pack, packm1);
}

// K3: MFMA fused attention; staging metadata read direct from global (saves a
// barrier); exp2-domain softmax; deferred 1/sum normalization.
__global__ __launch_bounds__(256, 4) void k_attn(const _Float16* __restrict__ qhf,
                                                 const _Float16* __restrict__ khf,
                                                 const _Float16* __restrict__ vhf,
                                                 const int4* __restrict__ meta_ws,
                                                 float* __restrict__ lse_ws,
                                                 _Float16* __restrict__ attn_ws) {
    __shared__ _Float16 Ksh[128 * 72];    // 18432 B; overlaid by Ph[64][136]
    __shared__ _Float16 Vt[64 * 136];     // 17408 B
    __shared__ int4 kmeta[128];

    int xcd = blockIdx.x & 7, slot = blockIdx.x >> 3;
    int b = xcd * 2 + (slot >> 8);
    int rem = slot & 255, n = rem >> 2, r = rem & 3;
    int tid = threadIdx.x;
    int w = tid >> 6, lane = tid & 63, quad = lane >> 4, l15 = lane & 15;
    int hibase = (b * 4 + r) * L_;
    const int4* mp = meta_ws + hibase;
    int nprev = (n + 63) & 63;

    if (tid < 128) {   // publish kmeta for post-QK mask phase (no barrier needed yet)
        int j = tid;
        int spos = (j < 64) ? (nprev * 64 + j) : (n * 64 + (j - 64));
        kmeta[j] = mp[spos];
    }
    {   // stage K: gathered f16 copy, metadata .y direct from global
        int j = tid >> 1, dh = (tid & 1) * 32;
        int spos = (j < 64) ? (nprev * 64 + j) : (n * 64 + (j - 64));
        int ky = mp[spos].y;
        const _Float16* src = khf + ((size_t)(b * L_ + ky)) * 64 + dh;
        #pragma unroll
        for (int g = 0; g < 4; g++)
            *(f16x8*)&Ksh[j * 72 + dh + g * 8] = *(const f16x8*)(src + g * 8);
    }
    {   // stage V^T: thread = (row-pair m, d-quarter sub)
        int m = tid >> 2, sub = tid & 3;
        int j0 = 2 * m, j1 = 2 * m + 1;
        int sp0 = (j0 < 64) ? (nprev * 64 + j0) : (n * 64 + (j0 - 64));
        int sp1 = (j1 < 64) ? (nprev * 64 + j1) : (n * 64 + (j1 - 64));
        int y0 = mp[sp0].y, y1 = mp[sp1].y;
        const _Float16* v0 = vhf + ((size_t)(b * L_ + y0)) * 64 + sub * 16;
        const _Float16* v1 = vhf + ((size_t)(b * L_ + y1)) * 64 + sub * 16;
        f16x8 a00 = *(const f16x8*)v0, a01 = *(const f16x8*)(v0 + 8);
        f16x8 a10 = *(const f16x8*)v1, a11 = *(const f16x8*)(v1 + 8);
        #pragma unroll
        for (int d = 0; d < 8; d++) {
            f16x2 hv = { a00[d], a10[d] };
            *(f16x2*)&Vt[(sub * 16 + d) * 136 + 2 * m] = hv;
            f16x2 hw = { a01[d], a11[d] };
            *(f16x2*)&Vt[(sub * 16 + 8 + d) * 136 + 2 * m] = hw;
        }
    }

    // Q A-frags direct from qhf (gathered 16B loads)
    int qy = mp[n * 64 + w * 16 + l15].y;
    const _Float16* qp = qhf + ((size_t)(b * L_ + qy)) * 64;
    f16x8 afr[2];
    afr[0] = *(const f16x8*)(qp + quad * 8);
    afr[1] = *(const f16x8*)(qp + 32 + quad * 8);
    __syncthreads();

    f32x4 acc[8];
    #pragma unroll
    for (int jt = 0; jt < 8; jt++) acc[jt] = (f32x4){0.f, 0.f, 0.f, 0.f};
    #pragma unroll
    for (int jt = 0; jt < 8; jt++) {
        #pragma unroll
        for (int kt = 0; kt < 2; kt++) {
            f16x8 bfr = *(const f16x8*)&Ksh[(jt * 16 + l15) * 72 + kt * 32 + quad * 8];
            acc[jt] = __builtin_amdgcn_mfma_f32_16x16x32_f16(afr[kt], bfr, acc[jt], 0, 0, 0);
        }
    }

    int4 qm4[4], km4[8];
    #pragma unroll
    for (int reg = 0; reg < 4; reg++) qm4[reg] = kmeta[64 + w * 16 + quad * 4 + reg];
    #pragma unroll
    for (int jt = 0; jt < 8; jt++) km4[jt] = kmeta[jt * 16 + l15];
    __syncthreads();                      // QK reads of Ksh done -> overlay

    _Float16* Ph = Ksh;
    float lse_r[4], inv_r[4];
    #pragma unroll
    for (int reg = 0; reg < 4; reg++) {
        float s[8];
        #pragma unroll
        for (int jt = 0; jt < 8; jt++) {
            float v = acc[jt][reg];
            if (km4[jt].x != qm4[reg].x) v = -1.4426951e9f;   // -1e9 * log2e
            if (qm4[reg].y < km4[jt].y)  v = -1.4426951e9f;
            if (qm4[reg].y == km4[jt].y) v = -144269.50f;     // -1e5 * log2e
            s[jt] = v;
        }
        float m = s[0];
        #pragma unroll
        for (int jt = 1; jt < 8; jt++) m = fmaxf(m, s[jt]);
        #pragma unroll
        for (int off = 1; off < 16; off <<= 1) m = fmaxf(m, __shfl_xor(m, off));
        float te[8], sum = 0.f;
        #pragma unroll
        for (int jt = 0; jt < 8; jt++) { te[jt] = __builtin_amdgcn_exp2f(s[jt] - m); sum += te[jt]; }
        #pragma unroll
        for (int off = 1; off < 16; off <<= 1) sum += __shfl_xor(sum, off);
        inv_r[reg] = __builtin_amdgcn_rcpf(sum);
        lse_r[reg] = m * 0.6931472f + __logf(sum);
        int i = w * 16 + quad * 4 + reg;
        #pragma unroll
        for (int jt = 0; jt < 8; jt++) {
            int z1 = km4[jt].z ^ qm4[reg].z;
            int z2 = km4[jt].z ^ qm4[reg].w;
            int nz = __popc((z1 + 0x7f7f7f7f) & 0x80808080)
                   + __popc((z2 + 0x7f7f7f7f) & 0x80808080);
            float p = te[jt] * __builtin_amdgcn_rcpf((float)(8 - nz));
            Ph[i * 136 + jt * 16 + l15] = (_Float16)p;
        }
    }
    if (l15 == 0) {
        #pragma unroll
        for (int reg = 0; reg < 4; reg++)
            lse_ws[hibase + qm4[reg].y] = lse_r[reg];
    }
    __syncthreads();

    f32x4 oacc[4];
    #pragma unroll
    for (int nt = 0; nt < 4; nt++) oacc[nt] = (f32x4){0.f, 0.f, 0.f, 0.f};
    #pragma unroll
    for (int kt = 0; kt < 4; kt++) {
        f16x8 pa = *(const f16x8*)&Ph[(w * 16 + l15) * 136 + kt * 32 + quad * 8];
        #pragma unroll
        for (int nt = 0; nt < 4; nt++) {
            f16x8 vb = *(const f16x8*)&Vt[(nt * 16 + l15) * 136 + kt * 32 + quad * 8];
            oacc[nt] = __builtin_amdgcn_mfma_f32_16x16x32_f16(pa, vb, oacc[nt], 0, 0, 0);
        }
    }
    #pragma unroll
    for (int reg = 0; reg < 4; reg++) {
        size_t base = (((size_t)(b * 4 + r)) * L_ + qm4[reg].y) * 64;
        #pragma unroll
        for (int nt = 0; nt < 4; nt++)
            attn_ws[base + nt * 16 + l15] = (_Float16)(oacc[nt][reg] * inv_r[reg]);
    }
}

// K4a: per (b,r) softmax-over-L stats of lse
__global__ __launch_bounds__(256) void k_rw(const float* __restrict__ lse_ws,
                                            float* __restrict__ rwmax,
                                            float* __restrict__ rwsum) {
    __shared__ float  red[256];
    __shared__ double redd[256];
    int br = blockIdx.x;
    const float* lp = lse_ws + (size_t)br * L_;
    int t = threadIdx.x;
    float m = -1e30f;
    for (int k = t; k < L_; k += 256) m = fmaxf(m, lp[k]);
    red[t] = m; __syncthreads();
    for (int s2 = 128; s2 > 0; s2 >>= 1) {
        if (t < s2) red[t] = fmaxf(red[t], red[t + s2]);
        __syncthreads();
    }
    float mm = red[0];
    double s = 0.0;
    for (int k = t; k < L_; k += 256) s += (double)expf(lp[k] - mm);
    redd[t] = s; __syncthreads();
    for (int s2 = 128; s2 > 0; s2 >>= 1) {
        if (t < s2) redd[t] += redd[t + s2];
        __syncthreads();
    }
    if (t == 0) { rwmax[br] = mm; rwsum[br] = (float)redd[0]; }
}

// K4b: vectorized combine — thread = (b,l, d-octet)
__global__ __launch_bounds__(256) void k_out(const _Float16* __restrict__ attn_ws,
                                             const float* __restrict__ lse_ws,
                                             const float* __restrict__ rwmax,
                                             const float* __restrict__ rwsum,
                                             float* __restrict__ out) {
    int gid = blockIdx.x * 256 + threadIdx.x;   // B*L*8
    int g = gid & 7;
    size_t row = (size_t)(gid >> 3);            // b*L + l
    int b = (int)(row >> 12), l = (int)(row & 4095);
    float o[8];
    #pragma unroll
    for (int k = 0; k < 8; k++) o[k] = 0.f;
    #pragma unroll
    for (int r = 0; r < 4; r++) {
        int br = b * 4 + r;
        float wgt = __expf(lse_ws[(size_t)br * L_ + l] - rwmax[br])
                  * __builtin_amdgcn_rcpf(rwsum[br]);
        f16x8 av = *(const f16x8*)&attn_ws[(((size_t)br * L_ + l) << 6) + g * 8];
        #pragma unroll
        for (int k = 0; k < 8; k++) o[k] += (float)av[k] * wgt;
    }
    float4* op = (float4*)(out + row * 64 + g * 8);
    op[0] = make_float4(o[0], o[1], o[2], o[3]);
    op[1] = make_float4(o[4], o[5], o[6], o[7]);
}

extern "C" void kernel_launch(void* const* d_in, const int* in_sizes, int n_in,
                              void* d_out, int out_size, void* d_ws, size_t ws_size,
                              hipStream_t stream) {
    const float* query = (const float*)d_in[0];
    const float* value = (const float*)d_in[1];
    const float* rm    = (const float*)d_in[2];
    char* ws = (char*)d_ws;
    double*    rmn    = (double*)ws;
    int*       h_ws   = (int*)(ws + ((size_t)1 << 20));
    int*       oi_ws  = (int*)(ws + ((size_t)3 << 20));
    float*     lse_ws = (float*)(ws + ((size_t)4 << 20));
    float*     rwmax  = (float*)(ws + ((size_t)5 << 20));
    float*     rwsum  = (float*)(ws + ((size_t)5 << 20) + 256);
    int*       fix_cnt= (int*)(ws + ((size_t)5 << 20) + 512);
    int*       fix_list=(int*)(ws + ((size_t)5 << 20) + 1024);
    _Float16*  attn_ws= (_Float16*)(ws + ((size_t)6 << 20));
    _Float16*  rhi_g  = (_Float16*)(ws + ((size_t)40 << 20));
    _Float16*  rlo_g  = (_Float16*)(ws + ((size_t)40 << 20) + ((size_t)1 << 19));
    int4*      meta_ws= (int4*)(ws + ((size_t)41 << 20));
    _Float16*  qhf    = (_Float16*)(ws + ((size_t)45 << 20));
    _Float16*  khf    = (_Float16*)(ws + ((size_t)53 << 20));
    _Float16*  vhf    = (_Float16*)(ws + ((size_t)61 << 20));
    float*     out    = (float*)d_out;

    hipLaunchKernelGGL(k_rmnorm, dim3(2048), dim3(64),  0, stream, rm, rmn, rhi_g, rlo_g, fix_cnt);
    hipLaunchKernelGGL(k_hash,   dim3(1024), dim3(256), 0, stream, query, value, rhi_g, rlo_g,
                       h_ws, fix_cnt, fix_list, qhf, khf, vhf);
    hipLaunchKernelGGL(k_fix,    dim3(64),   dim3(64),  0, stream, query, rmn,
                       fix_cnt, fix_list, h_ws);
    hipLaunchKernelGGL(k_sort,   dim3(64),   dim3(256), 0, stream, h_ws, oi_ws);
    hipLaunchKernelGGL(k_meta,   dim3(1024), dim3(256), 0, stream, h_ws, oi_ws, meta_ws);
    hipLaunchKernelGGL(k_attn,   dim3(4096), dim3(256), 0, stream,
                       qhf, khf, vhf, meta_ws, lse_ws, attn_ws);
    hipLaunchKernelGGL(k_rw,     dim3(64),   dim3(256), 0, stream, lse_ws, rwmax, rwsum);
    hipLaunchKernelGGL(k_out,    dim3(2048), dim3(256), 0, stream,
                       attn_ws, lse_ws, rwmax, rwsum, out);
}

// Round 2
// 162.900 us; speedup vs baseline: 1.0458x; 1.0106x over previous
//
#include <hip/hip_runtime.h>
#include <math.h>

#define B_  16
#define L_  4096
#define D_  64
#define R_  4
#define NB_ 64
#define BL_ 64
#define FIXCAP 8192

typedef _Float16 f16x8 __attribute__((ext_vector_type(8)));
typedef _Float16 f16x2 __attribute__((ext_vector_type(2)));
typedef float    f32x4 __attribute__((ext_vector_type(4)));

// ---------------- ws layout ----------------
// [0MB,1MB)     rmn    double   [B][R][32][64]
// [1MB,2MB)     h      int      [B][R][L]
// [2MB,3MB)     hi     int      [B][R][L]  sorted pos -> original idx
// [3MB,4MB)     oi     int      [B][R][L]  original idx -> sorted pos
// [4MB,5MB)     lse    float    [B][R][L]   (original index)
// [5MB,+256)    rwmax float[64]; [+256,+512) rwsum; [+512] fix_cnt; [+1024,) fix_list
// [6MB,40MB)    attn   _Float16 [B][R][L][64]  (original index)
// [40MB,+256K)  rhi    _Float16 [B][128][64]
// [40.5MB,+256K)rlo    _Float16 [B][128][64]
// [41MB,45MB)   meta   int4     [B*R][L]
// [45MB,53MB)   qhf    _Float16 [B][L][64]   raw q, f16
// [53MB,61MB)   khf    _Float16 [B][L][64]   q/||q|| * log2e/8, f16   (log2 domain!)
// [61MB,69MB)   vhf    _Float16 [B][L][64]   v, f16

// K0: normalize rand_matrix along d, store fp64 + split-f16 copies; zero fix_cnt.
__global__ __launch_bounds__(64) void k_rmnorm(const float* __restrict__ rm,
                                               double* __restrict__ rmn,
                                               _Float16* __restrict__ rhi_g,
                                               _Float16* __restrict__ rlo_g,
                                               int* __restrict__ fix_cnt) {
    if (blockIdx.x == 0 && threadIdx.x == 0) *fix_cnt = 0;
    int blk = blockIdx.x;                 // b*128 + r*32 + n
    int b = blk >> 7, r = (blk >> 5) & 3, n = blk & 31;
    int d = threadIdx.x;
    double v = (double)rm[(((size_t)b * 64 + d) * 4 + r) * 32 + n];
    double sq = v * v;
    #pragma unroll
    for (int off = 32; off > 0; off >>= 1) sq += __shfl_down(sq, off);
    double tot = __shfl(sq, 0);
    double nv = v / sqrt(tot);
    rmn[(((size_t)b * 4 + r) * 32 + n) * 64 + d] = nv;
    float f = (float)nv;
    _Float16 hi = (_Float16)f;
    size_t gi = ((size_t)b * 128 + r * 32 + n) * 64 + d;
    rhi_g[gi] = hi;
    rlo_g[gi] = (_Float16)(f - (float)hi);
}

// K1: split-f16 MFMA hash + f16 tensor prep (qhf/khf/vhf); deferred exact fix list.
__global__ __launch_bounds__(256, 4) void k_hash(const float* __restrict__ q,
                                                 const float* __restrict__ value,
                                                 const _Float16* __restrict__ rhi_g,
                                                 const _Float16* __restrict__ rlo_g,
                                                 int* __restrict__ h_ws,
                                                 int* __restrict__ fix_cnt,
                                                 int* __restrict__ fix_list,
                                                 _Float16* __restrict__ qhf,
                                                 _Float16* __restrict__ khf,
                                                 _Float16* __restrict__ vhf) {
    __shared__ __align__(16) char smem[36864];
    _Float16* Rhi = (_Float16*)smem;            // [128][72]
    _Float16* Rlo = (_Float16*)(smem + 18432);  // [128][72]
    float*    Sc  = (float*)smem;               // overlay [64][133]

    int blk = blockIdx.x;                 // b*64 + chunk
    int b = blk >> 6, chunk = blk & 63;
    int tid = threadIdx.x;
    int w = tid >> 6, lane = tid & 63, quad = lane >> 4, l15 = lane & 15;

    {   // vhf prep: 64 rows of v -> f16 (streaming, no LDS)
        int row = chunk * 64 + (tid >> 2), sub = tid & 3;
        const float4* vp = (const float4*)(value + ((size_t)(b * L_ + row)) * 64 + sub * 16);
        f16x8 h0, h1;
        #pragma unroll
        for (int c = 0; c < 2; c++) {
            float4 t0 = vp[2 * c], t1 = vp[2 * c + 1];
            f16x8& hd = c ? h1 : h0;
            hd[0]=(_Float16)t0.x; hd[1]=(_Float16)t0.y; hd[2]=(_Float16)t0.z; hd[3]=(_Float16)t0.w;
            hd[4]=(_Float16)t1.x; hd[5]=(_Float16)t1.y; hd[6]=(_Float16)t1.z; hd[7]=(_Float16)t1.w;
        }
        _Float16* dst = vhf + ((size_t)(b * L_ + row)) * 64 + sub * 16;
        *(f16x8*)dst = h0;
        *(f16x8*)(dst + 8) = h1;
    }

    {   // stage R split halves
        int row = tid >> 1, dh = (tid & 1) * 32;
        const _Float16* sh = rhi_g + ((size_t)b * 128 + row) * 64 + dh;
        const _Float16* sl = rlo_g + ((size_t)b * 128 + row) * 64 + dh;
        #pragma unroll
        for (int g = 0; g < 4; g++) {
            *(f16x8*)&Rhi[row * 72 + dh + g * 8] = *(const f16x8*)(sh + g * 8);
            *(f16x8*)&Rlo[row * 72 + dh + g * 8] = *(const f16x8*)(sl + g * 8);
        }
    }

    int qrow = chunk * 64 + w * 16 + l15;
    const float* qp = q + ((size_t)(b * L_ + qrow)) * 64;
    float qv[16];
    #pragma unroll
    for (int kt = 0; kt < 2; kt++) {
        float4 t0 = *(const float4*)(qp + kt * 32 + quad * 8);
        float4 t1 = *(const float4*)(qp + kt * 32 + quad * 8 + 4);
        qv[8*kt+0]=t0.x; qv[8*kt+1]=t0.y; qv[8*kt+2]=t0.z; qv[8*kt+3]=t0.w;
        qv[8*kt+4]=t1.x; qv[8*kt+5]=t1.y; qv[8*kt+6]=t1.z; qv[8*kt+7]=t1.w;
    }
    f16x8 Ahi[2], Alo[2];
    #pragma unroll
    for (int kt = 0; kt < 2; kt++) {
        #pragma unroll
        for (int j = 0; j < 8; j++) {
            _Float16 hi = (_Float16)qv[8*kt+j];
            Ahi[kt][j] = hi;
            Alo[kt][j] = (_Float16)(qv[8*kt+j] - (float)hi);
        }
    }
    {   // qhf (raw f16) + khf (scaled f16, includes log2e for exp2-domain softmax)
        float ss = 0.f;
        #pragma unroll
        for (int j = 0; j < 16; j++) ss += qv[j] * qv[j];
        ss += __shfl_xor(ss, 16);
        ss += __shfl_xor(ss, 32);
        float nr = sqrtf(ss); if (nr < 1e-12f) nr = 1e-12f;
        float kscale = 0.18033688f / nr;   // 0.125 * log2(e)
        _Float16* qd = qhf + ((size_t)(b * L_ + qrow)) * 64;
        _Float16* kd = khf + ((size_t)(b * L_ + qrow)) * 64;
        #pragma unroll
        for (int kt = 0; kt < 2; kt++) {
            *(f16x8*)(qd + kt * 32 + quad * 8) = Ahi[kt];
            f16x8 hv;
            #pragma unroll
            for (int j = 0; j < 8; j++) hv[j] = (_Float16)(qv[8*kt+j] * kscale);
            *(f16x8*)(kd + kt * 32 + quad * 8) = hv;
        }
    }
    __syncthreads();

    f32x4 acc[8];
    #pragma unroll
    for (int jt = 0; jt < 8; jt++) acc[jt] = (f32x4){0.f, 0.f, 0.f, 0.f};
    #pragma unroll
    for (int jt = 0; jt < 8; jt++) {
        #pragma unroll
        for (int kt = 0; kt < 2; kt++) {
            f16x8 bh = *(const f16x8*)&Rhi[(jt * 16 + l15) * 72 + kt * 32 + quad * 8];
            f16x8 bl = *(const f16x8*)&Rlo[(jt * 16 + l15) * 72 + kt * 32 + quad * 8];
            acc[jt] = __builtin_amdgcn_mfma_f32_16x16x32_f16(Ahi[kt], bh, acc[jt], 0, 0, 0);
            acc[jt] = __builtin_amdgcn_mfma_f32_16x16x32_f16(Ahi[kt], bl, acc[jt], 0, 0, 0);
            acc[jt] = __builtin_amdgcn_mfma_f32_16x16x32_f16(Alo[kt], bh, acc[jt], 0, 0, 0);
        }
    }
    __syncthreads();

    #pragma unroll
    for (int jt = 0; jt < 8; jt++) {
        #pragma unroll
        for (int reg = 0; reg < 4; reg++)
            Sc[(w * 16 + quad * 4 + reg) * 133 + jt * 16 + l15] = acc[jt][reg];
    }
    __syncthreads();

    {
        // top-2 of |v| with sign-tagged argmax. Exact ties (|v| equal) always
        // satisfy v1-v2 < 4e-5 -> resolved by k_fix with reference tie order.
        int row = tid & 63, r = tid >> 6;
        const float* sp = &Sc[row * 133 + r * 32];
        float v1 = -1e30f, v2 = -1e30f; int i1 = 0;
        #pragma unroll
        for (int n = 0; n < 32; n++) {
            float v = sp[n];
            float a = fabsf(v);
            int cand = n | ((__float_as_uint(v) >> 26) & 32);
            if (a > v1) i1 = cand;
            v2 = __builtin_amdgcn_fmed3f(a, v1, v2);
            v1 = fmaxf(a, v1);
        }
        int l = chunk * 64 + row;
        h_ws[((size_t)(b * 4 + r)) * L_ + l] = i1;
        if (v1 - v2 < 4e-5f) {
            int slot = atomicAdd(fix_cnt, 1);
            if (slot < FIXCAP) fix_list[slot] = (b << 14) | (r << 12) | l;
        }
    }
}

// K1b: exact fp64 resolve, one wave per flagged row.
__global__ __launch_bounds__(64) void k_fix(const float* __restrict__ q,
                                            const double* __restrict__ rmn,
                                            const int* __restrict__ fix_cnt,
                                            const int* __restrict__ fix_list,
                                            int* __restrict__ h_ws) {
    int cnt = *fix_cnt; if (cnt > FIXCAP) cnt = FIXCAP;
    int lane = threadIdx.x;
    for (int i = blockIdx.x; i < cnt; i += gridDim.x) {
        int e = fix_list[i];
        int b = e >> 14, r = (e >> 12) & 3, l = e & 4095;
        int n = lane & 31;
        const double* rp = rmn + ((size_t)(b * 4 + r)) * 2048 + n * 64;
        const float* qr = q + ((size_t)(b * L_ + l)) * 64;
        double a0 = 0.0, a1 = 0.0, a2 = 0.0, a3 = 0.0;
        #pragma unroll
        for (int d = 0; d < 64; d += 4) {
            a0 += (double)qr[d]   * rp[d];
            a1 += (double)qr[d+1] * rp[d+1];
            a2 += (double)qr[d+2] * rp[d+2];
            a3 += (double)qr[d+3] * rp[d+3];
        }
        double acc = ((a0 + a1) + (a2 + a3));
        double v = (lane < 32) ? acc : -acc;
        int idx = lane;
        #pragma unroll
        for (int off = 1; off < 64; off <<= 1) {
            double ov = __shfl_xor(v, off);
            int   oidx = __shfl_xor(idx, off);
            if (ov > v || (ov == v && oidx < idx)) { v = ov; idx = oidx; }
        }
        if (lane == 0) h_ws[((size_t)(b * 4 + r)) * L_ + l] = idx;
    }
}

// K2: stable counting sort per (b,r) — 256 threads, keys in registers,
// per-thread-column histogram, hierarchical scan, LDS-staged coalesced oi AND hi.
__global__ __launch_bounds__(256) void k_sort(const int* __restrict__ h_ws,
                                              int* __restrict__ hi_ws,
                                              int* __restrict__ oi_ws) {
    __shared__ __align__(16) unsigned short cnt[64 * 257];   // [bucket][thread], stride 257
    __shared__ __align__(16) unsigned short oi_s[256 * 17];  // padded [t][k] staging
    __shared__ __align__(16) unsigned short hi_s[4096];      // sorted pos -> idx
    __shared__ int part[256];                                // [seg][bucket] bases

    int br = blockIdx.x;
    int t = threadIdx.x;
    const int* hp = h_ws + (size_t)br * L_;

    // zero histogram (16448 u16 = 8224 u32)
    unsigned int* cz = (unsigned int*)cnt;
    #pragma unroll
    for (int i = 0; i < 33; i++) {
        int idx = i * 256 + t;
        if (idx < 8224) cz[idx] = 0;
    }

    // load 16 keys into registers (coalesced int4)
    int key[16];
    const int4* hp4 = (const int4*)(hp + t * 16);
    #pragma unroll
    for (int g = 0; g < 4; g++) {
        int4 v = hp4[g];
        key[g*4+0] = v.x; key[g*4+1] = v.y; key[g*4+2] = v.z; key[g*4+3] = v.w;
    }
    __syncthreads();

    // per-thread histogram
    #pragma unroll
    for (int k = 0; k < 16; k++) {
        unsigned short* c = &cnt[key[k] * 257 + t];
        *c = (unsigned short)(*c + 1);
    }
    __syncthreads();

    // within-segment exclusive prefix: thread (u = t&63, s = t>>6) walks its
    // segment's 64 thread-columns of bucket u.
    int u = t & 63, s = t >> 6;
    {
        int run = 0;
        int base_idx = u * 257 + s * 64;
        #pragma unroll 16
        for (int i = 0; i < 64; i++) {
            int c = cnt[base_idx + i];
            cnt[base_idx + i] = (unsigned short)run;
            run += c;
        }
        part[s * 64 + u] = run;
    }
    __syncthreads();

    // wave 0: cross-segment and cross-bucket exclusive bases
    if (t < 64) {
        int p0 = part[t], p1 = part[64 + t], p2 = part[128 + t], p3 = part[192 + t];
        int tot = p0 + p1 + p2 + p3;
        int v = tot;
        #pragma unroll
        for (int off = 1; off < 64; off <<= 1) {
            int o = __shfl_up(v, off);
            if (t >= off) v += o;
        }
        int base = v - tot;              // exclusive over buckets
        part[t]       = base;
        part[64 + t]  = base + p0;
        part[128 + t] = base + p0 + p1;
        part[192 + t] = base + p0 + p1 + p2;
    }
    __syncthreads();

    // scatter: pos = bucket/segment base + within-segment offset (stable)
    int sbase = s * 64;
    #pragma unroll
    for (int k = 0; k < 16; k++) {
        int uk = key[k];
        unsigned short* c = &cnt[uk * 257 + t];
        int pos = part[sbase + uk] + *c;
        *c = (unsigned short)(*c + 1);
        int idx = t * 16 + k;
        oi_s[(idx >> 4) * 17 + (idx & 15)] = (unsigned short)pos;
        hi_s[pos] = (unsigned short)idx;    // LDS scatter (cheap), global stays coalesced
    }
    __syncthreads();

    // coalesced output
    int* op  = oi_ws + (size_t)br * L_;
    int* hp2 = hi_ws + (size_t)br * L_;
    #pragma unroll
    for (int k = 0; k < 16; k++) {
        int e = k * 256 + t;
        op[e]  = (int)oi_s[(e >> 4) * 17 + (e & 15)];
        hp2[e] = (int)hi_s[e];
    }
}

// K2b: per sorted position meta record — iterate over SORTED position so the
// one int4 write is coalesced; the small scattered 4B reads are L2-resident.
__global__ __launch_bounds__(256) void k_meta(const int* __restrict__ h_ws,
                                              const int* __restrict__ hi_ws,
                                              const int* __restrict__ oi_ws,
                                              int4* __restrict__ meta_ws) {
    int gid = blockIdx.x * 256 + threadIdx.x;
    int br = gid >> 12, spos = gid & 4095;
    int b = br >> 2;
    int p = hi_ws[(size_t)br * L_ + spos];
    int hh = h_ws[(size_t)br * L_ + p];
    int pack = 0, packm1 = 0;
    #pragma unroll
    for (int r2 = 0; r2 < 4; r2++) {
        int bk = oi_ws[((size_t)(b * 4 + r2)) * L_ + p] >> 6;
        pack   |= bk << (8 * r2);
        packm1 |= ((bk + 63) & 63) << (8 * r2);
    }
    meta_ws[(size_t)br * L_ + spos] = make_int4(hh, p, pack, packm1);
}

// K3: MFMA fused attention; single meta read fused into K-staging (publish to
// LDS); exp2-domain softmax; LDS-transposed epilogue so every global store
// instruction covers full 64B lines (kills write-allocate amplification).
__global__ __launch_bounds__(256, 4) void k_attn(const _Float16* __restrict__ qhf,
                                                 const _Float16* __restrict__ khf,
                                                 const _Float16* __restrict__ vhf,
                                                 const int4* __restrict__ meta_ws,
                                                 float* __restrict__ lse_ws,
                                                 _Float16* __restrict__ attn_ws) {
    __shared__ _Float16 Ksh[128 * 72];    // 18432 B; overlaid by Ph[64][136], then Pout[64][72]
    __shared__ _Float16 Vt[64 * 136];     // 17408 B
    __shared__ int4 kmeta[128];

    int xcd = blockIdx.x & 7, slot = blockIdx.x >> 3;
    int b = xcd * 2 + (slot >> 8);
    int rem = slot & 255, n = rem >> 2, r = rem & 3;
    int tid = threadIdx.x;
    int w = tid >> 6, lane = tid & 63, quad = lane >> 4, l15 = lane & 15;
    int hibase = (b * 4 + r) * L_;
    const int4* mp = meta_ws + hibase;
    int nprev = (n + 63) & 63;

    {   // stage K + publish kmeta (one meta read per thread, coalesced)
        int j = tid >> 1, dh = (tid & 1) * 32;
        int spos = (j < 64) ? (nprev * 64 + j) : (n * 64 + (j - 64));
        int4 me = mp[spos];
        if (dh == 0) kmeta[j] = me;
        const _Float16* src = khf + ((size_t)(b * L_ + me.y)) * 64 + dh;
        #pragma unroll
        for (int g = 0; g < 4; g++)
            *(f16x8*)&Ksh[j * 72 + dh + g * 8] = *(const f16x8*)(src + g * 8);
    }
    __syncthreads();   // b1: Ksh + kmeta ready

    {   // stage V^T: thread = (row-pair m, d-quarter sub); rows from kmeta
        int m = tid >> 2, sub = tid & 3;
        int y0 = kmeta[2 * m].y, y1 = kmeta[2 * m + 1].y;
        const _Float16* v0 = vhf + ((size_t)(b * L_ + y0)) * 64 + sub * 16;
        const _Float16* v1 = vhf + ((size_t)(b * L_ + y1)) * 64 + sub * 16;
        f16x8 a00 = *(const f16x8*)v0, a01 = *(const f16x8*)(v0 + 8);
        f16x8 a10 = *(const f16x8*)v1, a11 = *(const f16x8*)(v1 + 8);
        #pragma unroll
        for (int d = 0; d < 8; d++) {
            f16x2 hv = { a00[d], a10[d] };
            *(f16x2*)&Vt[(sub * 16 + d) * 136 + 2 * m] = hv;
            f16x2 hw = { a01[d], a11[d] };
            *(f16x2*)&Vt[(sub * 16 + 8 + d) * 136 + 2 * m] = hw;
        }
    }

    // Q A-frags direct from qhf (gathered 16B loads, row from kmeta)
    int qy = kmeta[64 + w * 16 + l15].y;
    const _Float16* qp = qhf + ((size_t)(b * L_ + qy)) * 64;
    f16x8 afr[2];
    afr[0] = *(const f16x8*)(qp + quad * 8);
    afr[1] = *(const f16x8*)(qp + 32 + quad * 8);

    // QK^T (Ksh ready since b1; Vt not read until PV)
    f32x4 acc[8];
    #pragma unroll
    for (int jt = 0; jt < 8; jt++) acc[jt] = (f32x4){0.f, 0.f, 0.f, 0.f};
    __builtin_amdgcn_s_setprio(1);
    #pragma unroll
    for (int jt = 0; jt < 8; jt++) {
        #pragma unroll
        for (int kt = 0; kt < 2; kt++) {
            f16x8 bfr = *(const f16x8*)&Ksh[(jt * 16 + l15) * 72 + kt * 32 + quad * 8];
            acc[jt] = __builtin_amdgcn_mfma_f32_16x16x32_f16(afr[kt], bfr, acc[jt], 0, 0, 0);
        }
    }
    __builtin_amdgcn_s_setprio(0);

    int4 qm4[4], km4[8];
    #pragma unroll
    for (int reg = 0; reg < 4; reg++) qm4[reg] = kmeta[64 + w * 16 + quad * 4 + reg];
    #pragma unroll
    for (int jt = 0; jt < 8; jt++) km4[jt] = kmeta[jt * 16 + l15];
    __syncthreads();   // b2: all QK reads of Ksh done -> overlay Ph

    _Float16* Ph = Ksh;
    float lse_r[4], inv_r[4];
    #pragma unroll
    for (int reg = 0; reg < 4; reg++) {
        float s[8];
        #pragma unroll
        for (int jt = 0; jt < 8; jt++) {
            float v = acc[jt][reg];
            if (km4[jt].x != qm4[reg].x) v = -1.4426951e9f;   // -1e9 * log2e
            if (qm4[reg].y < km4[jt].y)  v = -1.4426951e9f;
            if (qm4[reg].y == km4[jt].y) v = -144269.50f;     // -1e5 * log2e
            s[jt] = v;
        }
        float m = s[0];
        #pragma unroll
        for (int jt = 1; jt < 8; jt++) m = fmaxf(m, s[jt]);
        #pragma unroll
        for (int off = 1; off < 16; off <<= 1) m = fmaxf(m, __shfl_xor(m, off));
        float te[8], sum = 0.f;
        #pragma unroll
        for (int jt = 0; jt < 8; jt++) { te[jt] = __builtin_amdgcn_exp2f(s[jt] - m); sum += te[jt]; }
        #pragma unroll
        for (int off = 1; off < 16; off <<= 1) sum += __shfl_xor(sum, off);
        inv_r[reg] = __builtin_amdgcn_rcpf(sum);
        lse_r[reg] = m * 0.6931472f + __logf(sum);
        int i = w * 16 + quad * 4 + reg;
        #pragma unroll
        for (int jt = 0; jt < 8; jt++) {
            int z1 = km4[jt].z ^ qm4[reg].z;
            int z2 = km4[jt].z ^ qm4[reg].w;
            int nz = __popc((z1 + 0x7f7f7f7f) & 0x80808080)
                   + __popc((z2 + 0x7f7f7f7f) & 0x80808080);
            float p = te[jt] * __builtin_amdgcn_rcpf((float)(8 - nz));
            Ph[i * 136 + jt * 16 + l15] = (_Float16)p;
        }
    }
    if (l15 == 0) {
        #pragma unroll
        for (int reg = 0; reg < 4; reg++)
            lse_ws[hibase + qm4[reg].y] = lse_r[reg];
    }
    __syncthreads();   // b3: Ph ready

    f32x4 oacc[4];
    #pragma unroll
    for (int nt = 0; nt < 4; nt++) oacc[nt] = (f32x4){0.f, 0.f, 0.f, 0.f};
    __builtin_amdgcn_s_setprio(1);
    #pragma unroll
    for (int kt = 0; kt < 4; kt++) {
        f16x8 pa = *(const f16x8*)&Ph[(w * 16 + l15) * 136 + kt * 32 + quad * 8];
        #pragma unroll
        for (int nt = 0; nt < 4; nt++) {
            f16x8 vb = *(const f16x8*)&Vt[(nt * 16 + l15) * 136 + kt * 32 + quad * 8];
            oacc[nt] = __builtin_amdgcn_mfma_f32_16x16x32_f16(pa, vb, oacc[nt], 0, 0, 0);
        }
    }
    __builtin_amdgcn_s_setprio(0);
    __syncthreads();   // b4: all PV reads of Ph/Vt done -> overlay Pout

    // transpose epilogue: stage normalized output tile in LDS [64][72]
    _Float16* Pout = Ksh;
    #pragma unroll
    for (int nt = 0; nt < 4; nt++) {
        #pragma unroll
        for (int reg = 0; reg < 4; reg++) {
            int i = w * 16 + quad * 4 + reg;
            Pout[i * 72 + nt * 16 + l15] = (_Float16)(oacc[nt][reg] * inv_r[reg]);
        }
    }
    __syncthreads();   // b5: Pout ready

    {   // 4 threads per row, two 16B stores each: each instruction's 4-lane
        // cluster covers a FULL 64B line even though rows are scattered.
        int row = tid >> 2, part = tid & 3;
        int y = kmeta[64 + row].y;
        _Float16* dst = attn_ws + ((size_t)hibase + y) * 64;
        f16x8 v0 = *(const f16x8*)&Pout[row * 72 + part * 8];
        f16x8 v1 = *(const f16x8*)&Pout[row * 72 + 32 + part * 8];
        *(f16x8*)(dst + part * 8) = v0;
        *(f16x8*)(dst + 32 + part * 8) = v1;
    }
}

// K4a: per (b,r) softmax-over-L stats of lse
__global__ __launch_bounds__(256) void k_rw(const float* __restrict__ lse_ws,
                                            float* __restrict__ rwmax,
                                            float* __restrict__ rwsum) {
    __shared__ float  red[256];
    __shared__ double redd[256];
    int br = blockIdx.x;
    const float* lp = lse_ws + (size_t)br * L_;
    int t = threadIdx.x;
    float m = -1e30f;
    for (int k = t; k < L_; k += 256) m = fmaxf(m, lp[k]);
    red[t] = m; __syncthreads();
    for (int s2 = 128; s2 > 0; s2 >>= 1) {
        if (t < s2) red[t] = fmaxf(red[t], red[t + s2]);
        __syncthreads();
    }
    float mm = red[0];
    double s = 0.0;
    for (int k = t; k < L_; k += 256) s += (double)expf(lp[k] - mm);
    redd[t] = s; __syncthreads();
    for (int s2 = 128; s2 > 0; s2 >>= 1) {
        if (t < s2) redd[t] += redd[t + s2];
        __syncthreads();
    }
    if (t == 0) { rwmax[br] = mm; rwsum[br] = (float)redd[0]; }
}

// K4b: vectorized combine — thread = (b,l, d-octet)
__global__ __launch_bounds__(256) void k_out(const _Float16* __restrict__ attn_ws,
                                             const float* __restrict__ lse_ws,
                                             const float* __restrict__ rwmax,
                                             const float* __restrict__ rwsum,
                                             float* __restrict__ out) {
    int gid = blockIdx.x * 256 + threadIdx.x;   // B*L*8
    int g = gid & 7;
    size_t row = (size_t)(gid >> 3);            // b*L + l
    int b = (int)(row >> 12), l = (int)(row & 4095);
    float o[8];
    #pragma unroll
    for (int k = 0; k < 8; k++) o[k] = 0.f;
    #pragma unroll
    for (int r = 0; r < 4; r++) {
        int br = b * 4 + r;
        float wgt = __expf(lse_ws[(size_t)br * L_ + l] - rwmax[br])
                  * __builtin_amdgcn_rcpf(rwsum[br]);
        f16x8 av = *(const f16x8*)&attn_ws[(((size_t)br * L_ + l) << 6) + g * 8];
        #pragma unroll
        for (int k = 0; k < 8; k++) o[k] += (float)av[k] * wgt;
    }
    float4* op = (float4*)(out + row * 64 + g * 8);
    op[0] = make_float4(o[0], o[1], o[2], o[3]);
    op[1] = make_float4(o[4], o[5], o[6], o[7]);
}

extern "C" void kernel_launch(void* const* d_in, const int* in_sizes, int n_in,
                              void* d_out, int out_size, void* d_ws, size_t ws_size,
                              hipStream_t stream) {
    const float* query = (const float*)d_in[0];
    const float* value = (const float*)d_in[1];
    const float* rm    = (const float*)d_in[2];
    char* ws = (char*)d_ws;
    double*    rmn    = (double*)ws;
    int*       h_ws   = (int*)(ws + ((size_t)1 << 20));
    int*       hi_ws  = (int*)(ws + ((size_t)2 << 20));
    int*       oi_ws  = (int*)(ws + ((size_t)3 << 20));
    float*     lse_ws = (float*)(ws + ((size_t)4 << 20));
    float*     rwmax  = (float*)(ws + ((size_t)5 << 20));
    float*     rwsum  = (float*)(ws + ((size_t)5 << 20) + 256);
    int*       fix_cnt= (int*)(ws + ((size_t)5 << 20) + 512);
    int*       fix_list=(int*)(ws + ((size_t)5 << 20) + 1024);
    _Float16*  attn_ws= (_Float16*)(ws + ((size_t)6 << 20));
    _Float16*  rhi_g  = (_Float16*)(ws + ((size_t)40 << 20));
    _Float16*  rlo_g  = (_Float16*)(ws + ((size_t)40 << 20) + ((size_t)1 << 19));
    int4*      meta_ws= (int4*)(ws + ((size_t)41 << 20));
    _Float16*  qhf    = (_Float16*)(ws + ((size_t)45 << 20));
    _Float16*  khf    = (_Float16*)(ws + ((size_t)53 << 20));
    _Float16*  vhf    = (_Float16*)(ws + ((size_t)61 << 20));
    float*     out    = (float*)d_out;

    hipLaunchKernelGGL(k_rmnorm, dim3(2048), dim3(64),  0, stream, rm, rmn, rhi_g, rlo_g, fix_cnt);
    hipLaunchKernelGGL(k_hash,   dim3(1024), dim3(256), 0, stream, query, value, rhi_g, rlo_g,
                       h_ws, fix_cnt, fix_list, qhf, khf, vhf);
    hipLaunchKernelGGL(k_fix,    dim3(64),   dim3(64),  0, stream, query, rmn,
                       fix_cnt, fix_list, h_ws);
    hipLaunchKernelGGL(k_sort,   dim3(64),   dim3(256), 0, stream, h_ws, hi_ws, oi_ws);
    hipLaunchKernelGGL(k_meta,   dim3(1024), dim3(256), 0, stream, h_ws, hi_ws, oi_ws, meta_ws);
    hipLaunchKernelGGL(k_attn,   dim3(4096), dim3(256), 0, stream,
                       qhf, khf, vhf, meta_ws, lse_ws, attn_ws);
    hipLaunchKernelGGL(k_rw,     dim3(64),   dim3(256), 0, stream, lse_ws, rwmax, rwsum);
    hipLaunchKernelGGL(k_out,    dim3(2048), dim3(256), 0, stream,
                       attn_ws, lse_ws, rwmax, rwsum, out);
}

// Round 3
// 160.384 us; speedup vs baseline: 1.0622x; 1.0157x over previous
//
#include <hip/hip_runtime.h>
#include <math.h>

#define B_  16
#define L_  4096
#define D_  64
#define R_  4
#define NB_ 64
#define BL_ 64
#define FIXCAP 8192

typedef _Float16 f16x8 __attribute__((ext_vector_type(8)));
typedef _Float16 f16x2 __attribute__((ext_vector_type(2)));
typedef float    f32x4 __attribute__((ext_vector_type(4)));

// ---------------- ws layout ----------------
// [0MB,1MB)     rmn    double   [B][R][32][64]
// [1MB,2MB)     h      int      [B][R][L]
// [2MB,3MB)     (unused)
// [3MB,4MB)     oi     int      [B][R][L]  original idx -> sorted pos
// [4MB,5MB)     lse    float    [B][R][L]   (original index)
// [5MB,+256)    rwmax float[64]; [+256,+512) rwsum; [+512] fix_cnt; [+1024,) fix_list
// [5MB+256K)    bstart int     [B*R][64]   bucket -> first sorted pos
// [6MB,40MB)    attn   _Float16 [B][R][L][64]  (original index)
// [40MB,+256K)  rhi    _Float16 [B][128][64]
// [40.5MB,+256K)rlo    _Float16 [B][128][64]
// [41MB,45MB)   meta   int4     [B*R][L]  (.x=bucket_start_spos,.y=p,.z=pack,.w=packm1)
// [45MB,53MB)   qhf    _Float16 [B][L][64]   raw q, f16
// [53MB,61MB)   khf    _Float16 [B][L][64]   q/||q|| * log2e/8, f16   (log2 domain!)
// [61MB,69MB)   vhf    _Float16 [B][L][64]   v, f16

// K0: normalize rand_matrix along d, store fp64 + split-f16 copies; zero fix_cnt.
__global__ __launch_bounds__(64) void k_rmnorm(const float* __restrict__ rm,
                                               double* __restrict__ rmn,
                                               _Float16* __restrict__ rhi_g,
                                               _Float16* __restrict__ rlo_g,
                                               int* __restrict__ fix_cnt) {
    if (blockIdx.x == 0 && threadIdx.x == 0) *fix_cnt = 0;
    int blk = blockIdx.x;                 // b*128 + r*32 + n
    int b = blk >> 7, r = (blk >> 5) & 3, n = blk & 31;
    int d = threadIdx.x;
    double v = (double)rm[(((size_t)b * 64 + d) * 4 + r) * 32 + n];
    double sq = v * v;
    #pragma unroll
    for (int off = 32; off > 0; off >>= 1) sq += __shfl_down(sq, off);
    double tot = __shfl(sq, 0);
    double nv = v / sqrt(tot);
    rmn[(((size_t)b * 4 + r) * 32 + n) * 64 + d] = nv;
    float f = (float)nv;
    _Float16 hi = (_Float16)f;
    size_t gi = ((size_t)b * 128 + r * 32 + n) * 64 + d;
    rhi_g[gi] = hi;
    rlo_g[gi] = (_Float16)(f - (float)hi);
}

// K1: split-f16 MFMA hash + f16 tensor prep (qhf/khf/vhf); deferred exact fix list.
__global__ __launch_bounds__(256, 4) void k_hash(const float* __restrict__ q,
                                                 const float* __restrict__ value,
                                                 const _Float16* __restrict__ rhi_g,
                                                 const _Float16* __restrict__ rlo_g,
                                                 int* __restrict__ h_ws,
                                                 int* __restrict__ fix_cnt,
                                                 int* __restrict__ fix_list,
                                                 _Float16* __restrict__ qhf,
                                                 _Float16* __restrict__ khf,
                                                 _Float16* __restrict__ vhf) {
    __shared__ __align__(16) char smem[36864];
    _Float16* Rhi = (_Float16*)smem;            // [128][72]
    _Float16* Rlo = (_Float16*)(smem + 18432);  // [128][72]
    float*    Sc  = (float*)smem;               // overlay [64][133]

    int blk = blockIdx.x;                 // b*64 + chunk
    int b = blk >> 6, chunk = blk & 63;
    int tid = threadIdx.x;
    int w = tid >> 6, lane = tid & 63, quad = lane >> 4, l15 = lane & 15;

    {   // vhf prep: 64 rows of v -> f16 (streaming, no LDS)
        int row = chunk * 64 + (tid >> 2), sub = tid & 3;
        const float4* vp = (const float4*)(value + ((size_t)(b * L_ + row)) * 64 + sub * 16);
        f16x8 h0, h1;
        #pragma unroll
        for (int c = 0; c < 2; c++) {
            float4 t0 = vp[2 * c], t1 = vp[2 * c + 1];
            f16x8& hd = c ? h1 : h0;
            hd[0]=(_Float16)t0.x; hd[1]=(_Float16)t0.y; hd[2]=(_Float16)t0.z; hd[3]=(_Float16)t0.w;
            hd[4]=(_Float16)t1.x; hd[5]=(_Float16)t1.y; hd[6]=(_Float16)t1.z; hd[7]=(_Float16)t1.w;
        }
        _Float16* dst = vhf + ((size_t)(b * L_ + row)) * 64 + sub * 16;
        *(f16x8*)dst = h0;
        *(f16x8*)(dst + 8) = h1;
    }

    {   // stage R split halves
        int row = tid >> 1, dh = (tid & 1) * 32;
        const _Float16* sh = rhi_g + ((size_t)b * 128 + row) * 64 + dh;
        const _Float16* sl = rlo_g + ((size_t)b * 128 + row) * 64 + dh;
        #pragma unroll
        for (int g = 0; g < 4; g++) {
            *(f16x8*)&Rhi[row * 72 + dh + g * 8] = *(const f16x8*)(sh + g * 8);
            *(f16x8*)&Rlo[row * 72 + dh + g * 8] = *(const f16x8*)(sl + g * 8);
        }
    }

    int qrow = chunk * 64 + w * 16 + l15;
    const float* qp = q + ((size_t)(b * L_ + qrow)) * 64;
    float qv[16];
    #pragma unroll
    for (int kt = 0; kt < 2; kt++) {
        float4 t0 = *(const float4*)(qp + kt * 32 + quad * 8);
        float4 t1 = *(const float4*)(qp + kt * 32 + quad * 8 + 4);
        qv[8*kt+0]=t0.x; qv[8*kt+1]=t0.y; qv[8*kt+2]=t0.z; qv[8*kt+3]=t0.w;
        qv[8*kt+4]=t1.x; qv[8*kt+5]=t1.y; qv[8*kt+6]=t1.z; qv[8*kt+7]=t1.w;
    }
    f16x8 Ahi[2], Alo[2];
    #pragma unroll
    for (int kt = 0; kt < 2; kt++) {
        #pragma unroll
        for (int j = 0; j < 8; j++) {
            _Float16 hi = (_Float16)qv[8*kt+j];
            Ahi[kt][j] = hi;
            Alo[kt][j] = (_Float16)(qv[8*kt+j] - (float)hi);
        }
    }
    {   // qhf (raw f16) + khf (scaled f16, includes log2e for exp2-domain softmax)
        float ss = 0.f;
        #pragma unroll
        for (int j = 0; j < 16; j++) ss += qv[j] * qv[j];
        ss += __shfl_xor(ss, 16);
        ss += __shfl_xor(ss, 32);
        float nr = sqrtf(ss); if (nr < 1e-12f) nr = 1e-12f;
        float kscale = 0.18033688f / nr;   // 0.125 * log2(e)
        _Float16* qd = qhf + ((size_t)(b * L_ + qrow)) * 64;
        _Float16* kd = khf + ((size_t)(b * L_ + qrow)) * 64;
        #pragma unroll
        for (int kt = 0; kt < 2; kt++) {
            *(f16x8*)(qd + kt * 32 + quad * 8) = Ahi[kt];
            f16x8 hv;
            #pragma unroll
            for (int j = 0; j < 8; j++) hv[j] = (_Float16)(qv[8*kt+j] * kscale);
            *(f16x8*)(kd + kt * 32 + quad * 8) = hv;
        }
    }
    __syncthreads();

    f32x4 acc[8];
    #pragma unroll
    for (int jt = 0; jt < 8; jt++) acc[jt] = (f32x4){0.f, 0.f, 0.f, 0.f};
    #pragma unroll
    for (int jt = 0; jt < 8; jt++) {
        #pragma unroll
        for (int kt = 0; kt < 2; kt++) {
            f16x8 bh = *(const f16x8*)&Rhi[(jt * 16 + l15) * 72 + kt * 32 + quad * 8];
            f16x8 bl = *(const f16x8*)&Rlo[(jt * 16 + l15) * 72 + kt * 32 + quad * 8];
            acc[jt] = __builtin_amdgcn_mfma_f32_16x16x32_f16(Ahi[kt], bh, acc[jt], 0, 0, 0);
            acc[jt] = __builtin_amdgcn_mfma_f32_16x16x32_f16(Ahi[kt], bl, acc[jt], 0, 0, 0);
            acc[jt] = __builtin_amdgcn_mfma_f32_16x16x32_f16(Alo[kt], bh, acc[jt], 0, 0, 0);
        }
    }
    __syncthreads();

    #pragma unroll
    for (int jt = 0; jt < 8; jt++) {
        #pragma unroll
        for (int reg = 0; reg < 4; reg++)
            Sc[(w * 16 + quad * 4 + reg) * 133 + jt * 16 + l15] = acc[jt][reg];
    }
    __syncthreads();

    {
        // top-2 of |v| with sign-tagged argmax. Exact ties (|v| equal) always
        // satisfy v1-v2 < 4e-5 -> resolved by k_fix with reference tie order.
        int row = tid & 63, r = tid >> 6;
        const float* sp = &Sc[row * 133 + r * 32];
        float v1 = -1e30f, v2 = -1e30f; int i1 = 0;
        #pragma unroll
        for (int n = 0; n < 32; n++) {
            float v = sp[n];
            float a = fabsf(v);
            int cand = n | ((__float_as_uint(v) >> 26) & 32);
            if (a > v1) i1 = cand;
            v2 = __builtin_amdgcn_fmed3f(a, v1, v2);
            v1 = fmaxf(a, v1);
        }
        int l = chunk * 64 + row;
        h_ws[((size_t)(b * 4 + r)) * L_ + l] = i1;
        if (v1 - v2 < 4e-5f) {
            int slot = atomicAdd(fix_cnt, 1);
            if (slot < FIXCAP) fix_list[slot] = (b << 14) | (r << 12) | l;
        }
    }
}

// K1b: exact fp64 resolve, one wave per flagged row.
__global__ __launch_bounds__(64) void k_fix(const float* __restrict__ q,
                                            const double* __restrict__ rmn,
                                            const int* __restrict__ fix_cnt,
                                            const int* __restrict__ fix_list,
                                            int* __restrict__ h_ws) {
    int cnt = *fix_cnt; if (cnt > FIXCAP) cnt = FIXCAP;
    int lane = threadIdx.x;
    for (int i = blockIdx.x; i < cnt; i += gridDim.x) {
        int e = fix_list[i];
        int b = e >> 14, r = (e >> 12) & 3, l = e & 4095;
        int n = lane & 31;
        const double* rp = rmn + ((size_t)(b * 4 + r)) * 2048 + n * 64;
        const float* qr = q + ((size_t)(b * L_ + l)) * 64;
        double a0 = 0.0, a1 = 0.0, a2 = 0.0, a3 = 0.0;
        #pragma unroll
        for (int d = 0; d < 64; d += 4) {
            a0 += (double)qr[d]   * rp[d];
            a1 += (double)qr[d+1] * rp[d+1];
            a2 += (double)qr[d+2] * rp[d+2];
            a3 += (double)qr[d+3] * rp[d+3];
        }
        double acc = ((a0 + a1) + (a2 + a3));
        double v = (lane < 32) ? acc : -acc;
        int idx = lane;
        #pragma unroll
        for (int off = 1; off < 64; off <<= 1) {
            double ov = __shfl_xor(v, off);
            int   oidx = __shfl_xor(idx, off);
            if (ov > v || (ov == v && oidx < idx)) { v = ov; idx = oidx; }
        }
        if (lane == 0) h_ws[((size_t)(b * 4 + r)) * L_ + l] = idx;
    }
}

// K2: stable counting sort per (b,r) — 256 threads, keys in registers,
// per-thread-column histogram, hierarchical scan, LDS-staged coalesced oi;
// also emits per-bucket start positions (exclusive prefix).
__global__ __launch_bounds__(256) void k_sort(const int* __restrict__ h_ws,
                                              int* __restrict__ oi_ws,
                                              int* __restrict__ bstart_g) {
    __shared__ __align__(16) unsigned short cnt[64 * 257];   // [bucket][thread], stride 257
    __shared__ __align__(16) unsigned short oi_s[256 * 17];  // padded [t][k] staging
    __shared__ int part[256];                                // [seg][bucket] bases

    int br = blockIdx.x;
    int t = threadIdx.x;
    const int* hp = h_ws + (size_t)br * L_;

    // zero histogram (16448 u16 = 8224 u32)
    unsigned int* cz = (unsigned int*)cnt;
    #pragma unroll
    for (int i = 0; i < 33; i++) {
        int idx = i * 256 + t;
        if (idx < 8224) cz[idx] = 0;
    }

    // load 16 keys into registers (coalesced int4)
    int key[16];
    const int4* hp4 = (const int4*)(hp + t * 16);
    #pragma unroll
    for (int g = 0; g < 4; g++) {
        int4 v = hp4[g];
        key[g*4+0] = v.x; key[g*4+1] = v.y; key[g*4+2] = v.z; key[g*4+3] = v.w;
    }
    __syncthreads();

    // per-thread histogram
    #pragma unroll
    for (int k = 0; k < 16; k++) {
        unsigned short* c = &cnt[key[k] * 257 + t];
        *c = (unsigned short)(*c + 1);
    }
    __syncthreads();

    // within-segment exclusive prefix: thread (u = t&63, s = t>>6) walks its
    // segment's 64 thread-columns of bucket u.
    int u = t & 63, s = t >> 6;
    {
        int run = 0;
        int base_idx = u * 257 + s * 64;
        #pragma unroll 16
        for (int i = 0; i < 64; i++) {
            int c = cnt[base_idx + i];
            cnt[base_idx + i] = (unsigned short)run;
            run += c;
        }
        part[s * 64 + u] = run;
    }
    __syncthreads();

    // wave 0: cross-segment and cross-bucket exclusive bases
    if (t < 64) {
        int p0 = part[t], p1 = part[64 + t], p2 = part[128 + t], p3 = part[192 + t];
        int tot = p0 + p1 + p2 + p3;
        int v = tot;
        #pragma unroll
        for (int off = 1; off < 64; off <<= 1) {
            int o = __shfl_up(v, off);
            if (t >= off) v += o;
        }
        int base = v - tot;              // exclusive over buckets = first spos of bucket t
        bstart_g[br * 64 + t] = base;
        part[t]       = base;
        part[64 + t]  = base + p0;
        part[128 + t] = base + p0 + p1;
        part[192 + t] = base + p0 + p1 + p2;
    }
    __syncthreads();

    // scatter: pos = bucket/segment base + within-segment offset (stable)
    int sbase = s * 64;
    #pragma unroll
    for (int k = 0; k < 16; k++) {
        int uk = key[k];
        unsigned short* c = &cnt[uk * 257 + t];
        int pos = part[sbase + uk] + *c;
        *c = (unsigned short)(*c + 1);
        int idx = t * 16 + k;
        oi_s[(idx >> 4) * 17 + (idx & 15)] = (unsigned short)pos;
    }
    __syncthreads();

    // coalesced output
    int* op = oi_ws + (size_t)br * L_;
    #pragma unroll
    for (int k = 0; k < 16; k++) {
        int e = k * 256 + t;
        op[e] = (int)oi_s[(e >> 4) * 17 + (e & 15)];
    }
}

// K2b: per sorted position meta record — iterate over ORIGINAL index p so all
// heavy reads are coalesced; one scattered int4 store (L2/L3 absorbs).
// .x = bucket start spos (for k_attn's range mask), .y = p, .z/.w = packs.
__global__ __launch_bounds__(256) void k_meta(const int* __restrict__ h_ws,
                                              const int* __restrict__ oi_ws,
                                              const int* __restrict__ bstart_g,
                                              int4* __restrict__ meta_ws) {
    int gid = blockIdx.x * 256 + threadIdx.x;
    int br = gid >> 12, p = gid & 4095;
    int b = br >> 2, rme = br & 3;
    int hh = h_ws[(size_t)br * L_ + p];
    int pack = 0, packm1 = 0, mypos = 0;
    #pragma unroll
    for (int r2 = 0; r2 < 4; r2++) {
        int o = oi_ws[((size_t)(b * 4 + r2)) * L_ + p];
        if (r2 == rme) mypos = o;
        int bk = o >> 6;
        pack   |= bk << (8 * r2);
        packm1 |= ((bk + 63) & 63) << (8 * r2);
    }
    int sb = bstart_g[br * 64 + hh];   // 256B table per br, cache-hot
    meta_ws[(size_t)br * L_ + mypos] = make_int4(sb, p, pack, packm1);
}

// K3: MFMA fused attention. Range-based mask: sorted order within a bucket is
// causal order (stable sort over unique keys), so keep iff lo <= j < si with
// si = 64+i static and lo from the q's bucket-start spos. exp2-domain softmax;
// full-line LDS-transposed store epilogue.
__global__ __launch_bounds__(256, 4) void k_attn(const _Float16* __restrict__ qhf,
                                                 const _Float16* __restrict__ khf,
                                                 const _Float16* __restrict__ vhf,
                                                 const int4* __restrict__ meta_ws,
                                                 float* __restrict__ lse_ws,
                                                 _Float16* __restrict__ attn_ws) {
    __shared__ _Float16 Ksh[128 * 72];    // 18432 B; overlaid by Ph[64][136], then Pout[64][72]
    __shared__ _Float16 Vt[64 * 136];     // 17408 B
    __shared__ int4 kmeta[128];

    int xcd = blockIdx.x & 7, slot = blockIdx.x >> 3;
    int b = xcd * 2 + (slot >> 8);
    int rem = slot & 255, n = rem >> 2, r = rem & 3;
    int tid = threadIdx.x;
    int w = tid >> 6, lane = tid & 63, quad = lane >> 4, l15 = lane & 15;
    int hibase = (b * 4 + r) * L_;
    const int4* mp = meta_ws + hibase;
    int nprev = (n + 63) & 63;

    {   // stage K + publish kmeta (one meta read per thread, coalesced)
        int j = tid >> 1, dh = (tid & 1) * 32;
        int spos = (j < 64) ? (nprev * 64 + j) : (n * 64 + (j - 64));
        int4 me = mp[spos];
        if (dh == 0) kmeta[j] = me;
        const _Float16* src = khf + ((size_t)(b * L_ + me.y)) * 64 + dh;
        #pragma unroll
        for (int g = 0; g < 4; g++)
            *(f16x8*)&Ksh[j * 72 + dh + g * 8] = *(const f16x8*)(src + g * 8);
    }
    __syncthreads();   // b1: Ksh + kmeta ready

    {   // stage V^T: thread = (row-pair m, d-quarter sub); rows from kmeta
        int m = tid >> 2, sub = tid & 3;
        int y0 = kmeta[2 * m].y, y1 = kmeta[2 * m + 1].y;
        const _Float16* v0 = vhf + ((size_t)(b * L_ + y0)) * 64 + sub * 16;
        const _Float16* v1 = vhf + ((size_t)(b * L_ + y1)) * 64 + sub * 16;
        f16x8 a00 = *(const f16x8*)v0, a01 = *(const f16x8*)(v0 + 8);
        f16x8 a10 = *(const f16x8*)v1, a11 = *(const f16x8*)(v1 + 8);
        #pragma unroll
        for (int d = 0; d < 8; d++) {
            f16x2 hv = { a00[d], a10[d] };
            *(f16x2*)&Vt[(sub * 16 + d) * 136 + 2 * m] = hv;
            f16x2 hw = { a01[d], a11[d] };
            *(f16x2*)&Vt[(sub * 16 + 8 + d) * 136 + 2 * m] = hw;
        }
    }

    // Q A-frags direct from qhf (gathered 16B loads, row from kmeta)
    int qy = kmeta[64 + w * 16 + l15].y;
    const _Float16* qp = qhf + ((size_t)(b * L_ + qy)) * 64;
    f16x8 afr[2];
    afr[0] = *(const f16x8*)(qp + quad * 8);
    afr[1] = *(const f16x8*)(qp + 32 + quad * 8);

    // QK^T (Ksh ready since b1; Vt not read until PV)
    f32x4 acc[8];
    #pragma unroll
    for (int jt = 0; jt < 8; jt++) acc[jt] = (f32x4){0.f, 0.f, 0.f, 0.f};
    __builtin_amdgcn_s_setprio(1);
    #pragma unroll
    for (int jt = 0; jt < 8; jt++) {
        #pragma unroll
        for (int kt = 0; kt < 2; kt++) {
            f16x8 bfr = *(const f16x8*)&Ksh[(jt * 16 + l15) * 72 + kt * 32 + quad * 8];
            acc[jt] = __builtin_amdgcn_mfma_f32_16x16x32_f16(afr[kt], bfr, acc[jt], 0, 0, 0);
        }
    }
    __builtin_amdgcn_s_setprio(0);

    int4 qm4[4]; int km4z[8];
    #pragma unroll
    for (int reg = 0; reg < 4; reg++) qm4[reg] = kmeta[64 + w * 16 + quad * 4 + reg];
    #pragma unroll
    for (int jt = 0; jt < 8; jt++) km4z[jt] = kmeta[jt * 16 + l15].z;
    __syncthreads();   // b2: all QK reads of Ksh done -> overlay Ph

    _Float16* Ph = Ksh;
    float lse_r[4], inv_r[4];
    #pragma unroll
    for (int reg = 0; reg < 4; reg++) {
        // valid k-columns form the contiguous range [lo, si); self at si.
        int lo = qm4[reg].x - (n - 1) * 64;          // bucket start in column space
        int width = w * 16 + quad * 4 + reg + 64 - lo;   // si - lo  (>= 0 always)
        int jl = l15 - lo;
        float s[8];
        #pragma unroll
        for (int jt = 0; jt < 8; jt++) {
            float v = acc[jt][reg];
            int ju = jt * 16 + jl;                   // j - lo
            v = ((unsigned)ju < (unsigned)width) ? v : -1.4426951e9f;
            if (ju == width) v = -144269.50f;        // self: -1e5 * log2e
            s[jt] = v;
        }
        float m = s[0];
        #pragma unroll
        for (int jt = 1; jt < 8; jt++) m = fmaxf(m, s[jt]);
        #pragma unroll
        for (int off = 1; off < 16; off <<= 1) m = fmaxf(m, __shfl_xor(m, off));
        float te[8], sum = 0.f;
        #pragma unroll
        for (int jt = 0; jt < 8; jt++) { te[jt] = __builtin_amdgcn_exp2f(s[jt] - m); sum += te[jt]; }
        #pragma unroll
        for (int off = 1; off < 16; off <<= 1) sum += __shfl_xor(sum, off);
        inv_r[reg] = __builtin_amdgcn_rcpf(sum);
        lse_r[reg] = m * 0.6931472f + __logf(sum);
        int i = w * 16 + quad * 4 + reg;
        #pragma unroll
        for (int jt = 0; jt < 8; jt++) {
            int z1 = km4z[jt] ^ qm4[reg].z;
            int z2 = km4z[jt] ^ qm4[reg].w;
            int nz = __popc((z1 + 0x7f7f7f7f) & 0x80808080)
                   + __popc((z2 + 0x7f7f7f7f) & 0x80808080);
            float p = te[jt] * __builtin_amdgcn_rcpf((float)(8 - nz));
            Ph[i * 136 + jt * 16 + l15] = (_Float16)p;
        }
    }
    if (l15 == 0) {
        #pragma unroll
        for (int reg = 0; reg < 4; reg++)
            lse_ws[hibase + qm4[reg].y] = lse_r[reg];
    }
    __syncthreads();   // b3: Ph ready

    f32x4 oacc[4];
    #pragma unroll
    for (int nt = 0; nt < 4; nt++) oacc[nt] = (f32x4){0.f, 0.f, 0.f, 0.f};
    __builtin_amdgcn_s_setprio(1);
    #pragma unroll
    for (int kt = 0; kt < 4; kt++) {
        f16x8 pa = *(const f16x8*)&Ph[(w * 16 + l15) * 136 + kt * 32 + quad * 8];
        #pragma unroll
        for (int nt = 0; nt < 4; nt++) {
            f16x8 vb = *(const f16x8*)&Vt[(nt * 16 + l15) * 136 + kt * 32 + quad * 8];
            oacc[nt] = __builtin_amdgcn_mfma_f32_16x16x32_f16(pa, vb, oacc[nt], 0, 0, 0);
        }
    }
    __builtin_amdgcn_s_setprio(0);
    __syncthreads();   // b4: all PV reads of Ph/Vt done -> overlay Pout

    // transpose epilogue: stage normalized output tile in LDS [64][72]
    _Float16* Pout = Ksh;
    #pragma unroll
    for (int nt = 0; nt < 4; nt++) {
        #pragma unroll
        for (int reg = 0; reg < 4; reg++) {
            int i = w * 16 + quad * 4 + reg;
            Pout[i * 72 + nt * 16 + l15] = (_Float16)(oacc[nt][reg] * inv_r[reg]);
        }
    }
    __syncthreads();   // b5: Pout ready

    {   // 4 threads per row, two 16B stores each: each instruction's 4-lane
        // cluster covers a FULL 64B line even though rows are scattered.
        int row = tid >> 2, part = tid & 3;
        int y = kmeta[64 + row].y;
        _Float16* dst = attn_ws + ((size_t)hibase + y) * 64;
        f16x8 v0 = *(const f16x8*)&Pout[row * 72 + part * 8];
        f16x8 v1 = *(const f16x8*)&Pout[row * 72 + 32 + part * 8];
        *(f16x8*)(dst + part * 8) = v0;
        *(f16x8*)(dst + 32 + part * 8) = v1;
    }
}

// K4a: per (b,r) softmax-over-L stats of lse
__global__ __launch_bounds__(256) void k_rw(const float* __restrict__ lse_ws,
                                            float* __restrict__ rwmax,
                                            float* __restrict__ rwsum) {
    __shared__ float  red[256];
    __shared__ double redd[256];
    int br = blockIdx.x;
    const float* lp = lse_ws + (size_t)br * L_;
    int t = threadIdx.x;
    float m = -1e30f;
    for (int k = t; k < L_; k += 256) m = fmaxf(m, lp[k]);
    red[t] = m; __syncthreads();
    for (int s2 = 128; s2 > 0; s2 >>= 1) {
        if (t < s2) red[t] = fmaxf(red[t], red[t + s2]);
        __syncthreads();
    }
    float mm = red[0];
    double s = 0.0;
    for (int k = t; k < L_; k += 256) s += (double)expf(lp[k] - mm);
    redd[t] = s; __syncthreads();
    for (int s2 = 128; s2 > 0; s2 >>= 1) {
        if (t < s2) redd[t] += redd[t + s2];
        __syncthreads();
    }
    if (t == 0) { rwmax[br] = mm; rwsum[br] = (float)redd[0]; }
}

// K4b: vectorized combine — thread = (b,l, d-octet)
__global__ __launch_bounds__(256) void k_out(const _Float16* __restrict__ attn_ws,
                                             const float* __restrict__ lse_ws,
                                             const float* __restrict__ rwmax,
                                             const float* __restrict__ rwsum,
                                             float* __restrict__ out) {
    int gid = blockIdx.x * 256 + threadIdx.x;   // B*L*8
    int g = gid & 7;
    size_t row = (size_t)(gid >> 3);            // b*L + l
    int b = (int)(row >> 12), l = (int)(row & 4095);
    float o[8];
    #pragma unroll
    for (int k = 0; k < 8; k++) o[k] = 0.f;
    #pragma unroll
    for (int r = 0; r < 4; r++) {
        int br = b * 4 + r;
        float wgt = __expf(lse_ws[(size_t)br * L_ + l] - rwmax[br])
                  * __builtin_amdgcn_rcpf(rwsum[br]);
        f16x8 av = *(const f16x8*)&attn_ws[(((size_t)br * L_ + l) << 6) + g * 8];
        #pragma unroll
        for (int k = 0; k < 8; k++) o[k] += (float)av[k] * wgt;
    }
    float4* op = (float4*)(out + row * 64 + g * 8);
    op[0] = make_float4(o[0], o[1], o[2], o[3]);
    op[1] = make_float4(o[4], o[5], o[6], o[7]);
}

extern "C" void kernel_launch(void* const* d_in, const int* in_sizes, int n_in,
                              void* d_out, int out_size, void* d_ws, size_t ws_size,
                              hipStream_t stream) {
    const float* query = (const float*)d_in[0];
    const float* value = (const float*)d_in[1];
    const float* rm    = (const float*)d_in[2];
    char* ws = (char*)d_ws;
    double*    rmn    = (double*)ws;
    int*       h_ws   = (int*)(ws + ((size_t)1 << 20));
    int*       oi_ws  = (int*)(ws + ((size_t)3 << 20));
    float*     lse_ws = (float*)(ws + ((size_t)4 << 20));
    float*     rwmax  = (float*)(ws + ((size_t)5 << 20));
    float*     rwsum  = (float*)(ws + ((size_t)5 << 20) + 256);
    int*       fix_cnt= (int*)(ws + ((size_t)5 << 20) + 512);
    int*       fix_list=(int*)(ws + ((size_t)5 << 20) + 1024);
    int*       bstart = (int*)(ws + ((size_t)5 << 20) + ((size_t)256 << 10));
    _Float16*  attn_ws= (_Float16*)(ws + ((size_t)6 << 20));
    _Float16*  rhi_g  = (_Float16*)(ws + ((size_t)40 << 20));
    _Float16*  rlo_g  = (_Float16*)(ws + ((size_t)40 << 20) + ((size_t)1 << 19));
    int4*      meta_ws= (int4*)(ws + ((size_t)41 << 20));
    _Float16*  qhf    = (_Float16*)(ws + ((size_t)45 << 20));
    _Float16*  khf    = (_Float16*)(ws + ((size_t)53 << 20));
    _Float16*  vhf    = (_Float16*)(ws + ((size_t)61 << 20));
    float*     out    = (float*)d_out;

    hipLaunchKernelGGL(k_rmnorm, dim3(2048), dim3(64),  0, stream, rm, rmn, rhi_g, rlo_g, fix_cnt);
    hipLaunchKernelGGL(k_hash,   dim3(1024), dim3(256), 0, stream, query, value, rhi_g, rlo_g,
                       h_ws, fix_cnt, fix_list, qhf, khf, vhf);
    hipLaunchKernelGGL(k_fix,    dim3(64),   dim3(64),  0, stream, query, rmn,
                       fix_cnt, fix_list, h_ws);
    hipLaunchKernelGGL(k_sort,   dim3(64),   dim3(256), 0, stream, h_ws, oi_ws, bstart);
    hipLaunchKernelGGL(k_meta,   dim3(1024), dim3(256), 0, stream, h_ws, oi_ws, bstart, meta_ws);
    hipLaunchKernelGGL(k_attn,   dim3(4096), dim3(256), 0, stream,
                       qhf, khf, vhf, meta_ws, lse_ws, attn_ws);
    hipLaunchKernelGGL(k_rw,     dim3(64),   dim3(256), 0, stream, lse_ws, rwmax, rwsum);
    hipLaunchKernelGGL(k_out,    dim3(2048), dim3(256), 0, stream,
                       attn_ws, lse_ws, rwmax, rwsum, out);
}

// Round 5
// 160.167 us; speedup vs baseline: 1.0636x; 1.0014x over previous
//
#include <hip/hip_runtime.h>
#include <math.h>

#define B_  16
#define L_  4096
#define D_  64
#define R_  4
#define NB_ 64
#define BL_ 64
#define FIXCAP 8192

typedef _Float16 f16x8 __attribute__((ext_vector_type(8)));
typedef _Float16 f16x2 __attribute__((ext_vector_type(2)));
typedef float    f32x4 __attribute__((ext_vector_type(4)));

// ---------------- ws layout ----------------
// [0MB,1MB)     rmn    double   [B][R][32][64]
// [1MB,2MB)     h      int      [B][R][L]
// [3MB,4MB)     oi     int      [B][R][L]  original idx -> sorted pos
// [4MB,5MB)     lse    float    [B][R][L]   (original index)
// [5MB,+256)    rwmax float[64]; [+256,+512) rwsum; [+512] fix_cnt; [+1024,) fix_list
// [5MB+256K)    bstart int     [B*R][64]   bucket -> first sorted pos
// [6MB,40MB)    attn   _Float16 [B][R][L][64]  (original index)
// [40MB,+256K)  rhi    _Float16 [B][128][64]
// [40.5MB,+256K)rlo    _Float16 [B][128][64]
// [41MB,45MB)   meta   int4     [B*R][L]  (.x=bucket_start_spos,.y=p,.z=pack,.w=packm1)
// [45MB,+256K)  qscale float    [B][L]     ||q|| / (0.125*log2e)
// [53MB,61MB)   khf    _Float16 [B][L][64]   q/||q|| * log2e/8, f16   (log2 domain!)
// [61MB,69MB)   vhf    _Float16 [B][L][64]   v, f16

// K0: normalize rand_matrix along d, store fp64 + split-f16 copies; zero fix_cnt.
__global__ __launch_bounds__(64) void k_rmnorm(const float* __restrict__ rm,
                                               double* __restrict__ rmn,
                                               _Float16* __restrict__ rhi_g,
                                               _Float16* __restrict__ rlo_g,
                                               int* __restrict__ fix_cnt) {
    if (blockIdx.x == 0 && threadIdx.x == 0) *fix_cnt = 0;
    int blk = blockIdx.x;                 // b*128 + r*32 + n
    int b = blk >> 7, r = (blk >> 5) & 3, n = blk & 31;
    int d = threadIdx.x;
    double v = (double)rm[(((size_t)b * 64 + d) * 4 + r) * 32 + n];
    double sq = v * v;
    #pragma unroll
    for (int off = 32; off > 0; off >>= 1) sq += __shfl_down(sq, off);
    double tot = __shfl(sq, 0);
    double nv = v / sqrt(tot);
    rmn[(((size_t)b * 4 + r) * 32 + n) * 64 + d] = nv;
    float f = (float)nv;
    _Float16 hi = (_Float16)f;
    size_t gi = ((size_t)b * 128 + r * 32 + n) * 64 + d;
    rhi_g[gi] = hi;
    rlo_g[gi] = (_Float16)(f - (float)hi);
}

// K1: split-f16 MFMA hash + f16 tensor prep (khf/vhf + qscale); deferred exact fix list.
__global__ __launch_bounds__(256, 4) void k_hash(const float* __restrict__ q,
                                                 const float* __restrict__ value,
                                                 const _Float16* __restrict__ rhi_g,
                                                 const _Float16* __restrict__ rlo_g,
                                                 int* __restrict__ h_ws,
                                                 int* __restrict__ fix_cnt,
                                                 int* __restrict__ fix_list,
                                                 float* __restrict__ qscale_g,
                                                 _Float16* __restrict__ khf,
                                                 _Float16* __restrict__ vhf) {
    __shared__ __align__(16) char smem[36864];
    _Float16* Rhi = (_Float16*)smem;            // [128][72]
    _Float16* Rlo = (_Float16*)(smem + 18432);  // [128][72]
    float*    Sc  = (float*)smem;               // overlay [64][133]

    int blk = blockIdx.x;                 // b*64 + chunk
    int b = blk >> 6, chunk = blk & 63;
    int tid = threadIdx.x;
    int w = tid >> 6, lane = tid & 63, quad = lane >> 4, l15 = lane & 15;

    {   // vhf prep: 64 rows of v -> f16 (streaming, no LDS)
        int row = chunk * 64 + (tid >> 2), sub = tid & 3;
        const float4* vp = (const float4*)(value + ((size_t)(b * L_ + row)) * 64 + sub * 16);
        f16x8 h0, h1;
        #pragma unroll
        for (int c = 0; c < 2; c++) {
            float4 t0 = vp[2 * c], t1 = vp[2 * c + 1];
            f16x8& hd = c ? h1 : h0;
            hd[0]=(_Float16)t0.x; hd[1]=(_Float16)t0.y; hd[2]=(_Float16)t0.z; hd[3]=(_Float16)t0.w;
            hd[4]=(_Float16)t1.x; hd[5]=(_Float16)t1.y; hd[6]=(_Float16)t1.z; hd[7]=(_Float16)t1.w;
        }
        _Float16* dst = vhf + ((size_t)(b * L_ + row)) * 64 + sub * 16;
        *(f16x8*)dst = h0;
        *(f16x8*)(dst + 8) = h1;
    }

    {   // stage R split halves
        int row = tid >> 1, dh = (tid & 1) * 32;
        const _Float16* sh = rhi_g + ((size_t)b * 128 + row) * 64 + dh;
        const _Float16* sl = rlo_g + ((size_t)b * 128 + row) * 64 + dh;
        #pragma unroll
        for (int g = 0; g < 4; g++) {
            *(f16x8*)&Rhi[row * 72 + dh + g * 8] = *(const f16x8*)(sh + g * 8);
            *(f16x8*)&Rlo[row * 72 + dh + g * 8] = *(const f16x8*)(sl + g * 8);
        }
    }

    int qrow = chunk * 64 + w * 16 + l15;
    const float* qp = q + ((size_t)(b * L_ + qrow)) * 64;
    float qv[16];
    #pragma unroll
    for (int kt = 0; kt < 2; kt++) {
        float4 t0 = *(const float4*)(qp + kt * 32 + quad * 8);
        float4 t1 = *(const float4*)(qp + kt * 32 + quad * 8 + 4);
        qv[8*kt+0]=t0.x; qv[8*kt+1]=t0.y; qv[8*kt+2]=t0.z; qv[8*kt+3]=t0.w;
        qv[8*kt+4]=t1.x; qv[8*kt+5]=t1.y; qv[8*kt+6]=t1.z; qv[8*kt+7]=t1.w;
    }
    f16x8 Ahi[2], Alo[2];
    #pragma unroll
    for (int kt = 0; kt < 2; kt++) {
        #pragma unroll
        for (int j = 0; j < 8; j++) {
            _Float16 hi = (_Float16)qv[8*kt+j];
            Ahi[kt][j] = hi;
            Alo[kt][j] = (_Float16)(qv[8*kt+j] - (float)hi);
        }
    }
    {   // khf (normalized, scaled f16, log2-domain) + qscale
        float ss = 0.f;
        #pragma unroll
        for (int j = 0; j < 16; j++) ss += qv[j] * qv[j];
        ss += __shfl_xor(ss, 16);
        ss += __shfl_xor(ss, 32);
        float nr = sqrtf(ss); if (nr < 1e-12f) nr = 1e-12f;
        float kscale = 0.18033688f / nr;   // c = 0.125 * log2(e)
        if (quad == 0) qscale_g[(size_t)b * L_ + qrow] = nr * 5.5451774445f;  // nr / c
        _Float16* kd = khf + ((size_t)(b * L_ + qrow)) * 64;
        #pragma unroll
        for (int kt = 0; kt < 2; kt++) {
            f16x8 hv;
            #pragma unroll
            for (int j = 0; j < 8; j++) hv[j] = (_Float16)(qv[8*kt+j] * kscale);
            *(f16x8*)(kd + kt * 32 + quad * 8) = hv;
        }
    }
    __syncthreads();

    f32x4 acc[8];
    #pragma unroll
    for (int jt = 0; jt < 8; jt++) acc[jt] = (f32x4){0.f, 0.f, 0.f, 0.f};
    #pragma unroll
    for (int jt = 0; jt < 8; jt++) {
        #pragma unroll
        for (int kt = 0; kt < 2; kt++) {
            f16x8 bh = *(const f16x8*)&Rhi[(jt * 16 + l15) * 72 + kt * 32 + quad * 8];
            f16x8 bl = *(const f16x8*)&Rlo[(jt * 16 + l15) * 72 + kt * 32 + quad * 8];
            acc[jt] = __builtin_amdgcn_mfma_f32_16x16x32_f16(Ahi[kt], bh, acc[jt], 0, 0, 0);
            acc[jt] = __builtin_amdgcn_mfma_f32_16x16x32_f16(Ahi[kt], bl, acc[jt], 0, 0, 0);
            acc[jt] = __builtin_amdgcn_mfma_f32_16x16x32_f16(Alo[kt], bh, acc[jt], 0, 0, 0);
        }
    }
    __syncthreads();

    #pragma unroll
    for (int jt = 0; jt < 8; jt++) {
        #pragma unroll
        for (int reg = 0; reg < 4; reg++)
            Sc[(w * 16 + quad * 4 + reg) * 133 + jt * 16 + l15] = acc[jt][reg];
    }
    __syncthreads();

    {
        // top-2 of |v| with sign-tagged argmax. Exact ties (|v| equal) always
        // satisfy v1-v2 < 4e-5 -> resolved by k_fix with reference tie order.
        int row = tid & 63, r = tid >> 6;
        const float* sp = &Sc[row * 133 + r * 32];
        float v1 = -1e30f, v2 = -1e30f; int i1 = 0;
        #pragma unroll
        for (int n = 0; n < 32; n++) {
            float v = sp[n];
            float a = fabsf(v);
            int cand = n | ((__float_as_uint(v) >> 26) & 32);
            if (a > v1) i1 = cand;
            v2 = __builtin_amdgcn_fmed3f(a, v1, v2);
            v1 = fmaxf(a, v1);
        }
        int l = chunk * 64 + row;
        h_ws[((size_t)(b * 4 + r)) * L_ + l] = i1;
        if (v1 - v2 < 4e-5f) {
            int slot = atomicAdd(fix_cnt, 1);
            if (slot < FIXCAP) fix_list[slot] = (b << 14) | (r << 12) | l;
        }
    }
}

// K1b: exact fp64 resolve, one wave per flagged row.
__global__ __launch_bounds__(64) void k_fix(const float* __restrict__ q,
                                            const double* __restrict__ rmn,
                                            const int* __restrict__ fix_cnt,
                                            const int* __restrict__ fix_list,
                                            int* __restrict__ h_ws) {
    int cnt = *fix_cnt; if (cnt > FIXCAP) cnt = FIXCAP;
    int lane = threadIdx.x;
    for (int i = blockIdx.x; i < cnt; i += gridDim.x) {
        int e = fix_list[i];
        int b = e >> 14, r = (e >> 12) & 3, l = e & 4095;
        int n = lane & 31;
        const double* rp = rmn + ((size_t)(b * 4 + r)) * 2048 + n * 64;
        const float* qr = q + ((size_t)(b * L_ + l)) * 64;
        double a0 = 0.0, a1 = 0.0, a2 = 0.0, a3 = 0.0;
        #pragma unroll
        for (int d = 0; d < 64; d += 4) {
            a0 += (double)qr[d]   * rp[d];
            a1 += (double)qr[d+1] * rp[d+1];
            a2 += (double)qr[d+2] * rp[d+2];
            a3 += (double)qr[d+3] * rp[d+3];
        }
        double acc = ((a0 + a1) + (a2 + a3));
        double v = (lane < 32) ? acc : -acc;
        int idx = lane;
        #pragma unroll
        for (int off = 1; off < 64; off <<= 1) {
            double ov = __shfl_xor(v, off);
            int   oidx = __shfl_xor(idx, off);
            if (ov > v || (ov == v && oidx < idx)) { v = ov; idx = oidx; }
        }
        if (lane == 0) h_ws[((size_t)(b * 4 + r)) * L_ + l] = idx;
    }
}

// K2: stable counting sort per (b,r) — 256 threads, keys in registers,
// per-thread-column histogram, hierarchical scan, LDS-staged coalesced oi;
// also emits per-bucket start positions (exclusive prefix).
__global__ __launch_bounds__(256) void k_sort(const int* __restrict__ h_ws,
                                              int* __restrict__ oi_ws,
                                              int* __restrict__ bstart_g) {
    __shared__ __align__(16) unsigned short cnt[64 * 257];   // [bucket][thread], stride 257
    __shared__ __align__(16) unsigned short oi_s[256 * 17];  // padded [t][k] staging
    __shared__ int part[256];                                // [seg][bucket] bases

    int br = blockIdx.x;
    int t = threadIdx.x;
    const int* hp = h_ws + (size_t)br * L_;

    // zero histogram (16448 u16 = 8224 u32)
    unsigned int* cz = (unsigned int*)cnt;
    #pragma unroll
    for (int i = 0; i < 33; i++) {
        int idx = i * 256 + t;
        if (idx < 8224) cz[idx] = 0;
    }

    // load 16 keys into registers (coalesced int4)
    int key[16];
    const int4* hp4 = (const int4*)(hp + t * 16);
    #pragma unroll
    for (int g = 0; g < 4; g++) {
        int4 v = hp4[g];
        key[g*4+0] = v.x; key[g*4+1] = v.y; key[g*4+2] = v.z; key[g*4+3] = v.w;
    }
    __syncthreads();

    // per-thread histogram
    #pragma unroll
    for (int k = 0; k < 16; k++) {
        unsigned short* c = &cnt[key[k] * 257 + t];
        *c = (unsigned short)(*c + 1);
    }
    __syncthreads();

    // within-segment exclusive prefix: thread (u = t&63, s = t>>6) walks its
    // segment's 64 thread-columns of bucket u.
    int u = t & 63, s = t >> 6;
    {
        int run = 0;
        int base_idx = u * 257 + s * 64;
        #pragma unroll 16
        for (int i = 0; i < 64; i++) {
            int c = cnt[base_idx + i];
            cnt[base_idx + i] = (unsigned short)run;
            run += c;
        }
        part[s * 64 + u] = run;
    }
    __syncthreads();

    // wave 0: cross-segment and cross-bucket exclusive bases
    if (t < 64) {
        int p0 = part[t], p1 = part[64 + t], p2 = part[128 + t], p3 = part[192 + t];
        int tot = p0 + p1 + p2 + p3;
        int v = tot;
        #pragma unroll
        for (int off = 1; off < 64; off <<= 1) {
            int o = __shfl_up(v, off);
            if (t >= off) v += o;
        }
        int base = v - tot;              // exclusive over buckets = first spos of bucket t
        bstart_g[br * 64 + t] = base;
        part[t]       = base;
        part[64 + t]  = base + p0;
        part[128 + t] = base + p0 + p1;
        part[192 + t] = base + p0 + p1 + p2;
    }
    __syncthreads();

    // scatter: pos = bucket/segment base + within-segment offset (stable)
    int sbase = s * 64;
    #pragma unroll
    for (int k = 0; k < 16; k++) {
        int uk = key[k];
        unsigned short* c = &cnt[uk * 257 + t];
        int pos = part[sbase + uk] + *c;
        *c = (unsigned short)(*c + 1);
        int idx = t * 16 + k;
        oi_s[(idx >> 4) * 17 + (idx & 15)] = (unsigned short)pos;
    }
    __syncthreads();

    // coalesced output
    int* op = oi_ws + (size_t)br * L_;
    #pragma unroll
    for (int k = 0; k < 16; k++) {
        int e = k * 256 + t;
        op[e] = (int)oi_s[(e >> 4) * 17 + (e & 15)];
    }
}

// K2b: per sorted position meta record — iterate over ORIGINAL index p so all
// heavy reads are coalesced; one scattered int4 store (L2/L3 absorbs).
// .x = bucket start spos (for k_attn's range mask), .y = p, .z/.w = packs.
__global__ __launch_bounds__(256) void k_meta(const int* __restrict__ h_ws,
                                              const int* __restrict__ oi_ws,
                                              const int* __restrict__ bstart_g,
                                              int4* __restrict__ meta_ws) {
    int gid = blockIdx.x * 256 + threadIdx.x;
    int br = gid >> 12, p = gid & 4095;
    int b = br >> 2, rme = br & 3;
    int hh = h_ws[(size_t)br * L_ + p];
    int pack = 0, packm1 = 0, mypos = 0;
    #pragma unroll
    for (int r2 = 0; r2 < 4; r2++) {
        int o = oi_ws[((size_t)(b * 4 + r2)) * L_ + p];
        if (r2 == rme) mypos = o;
        int bk = o >> 6;
        pack   |= bk << (8 * r2);
        packm1 |= ((bk + 63) & 63) << (8 * r2);
    }
    int sb = bstart_g[br * 64 + hh];   // 256B table per br, cache-hot
    meta_ws[(size_t)br * L_ + mypos] = make_int4(sb, p, pack, packm1);
}

// K3: MFMA fused attention. A-frags come straight from Ksh rows 64..127 (the
// current tile IS the q rows, khf-scaled); per-q-row qscale multiply restores
// the score. Range-based causal mask; exp2-domain softmax; full-line store
// epilogue. Vt is [64 d-rows][128 j-cols] stride 136 (DO NOT shrink: j spans
// 128 columns — round-4's stride-72 overflow was a NaN bug).
__global__ __launch_bounds__(256, 4) void k_attn(const float* __restrict__ qscale_g,
                                                 const _Float16* __restrict__ khf,
                                                 const _Float16* __restrict__ vhf,
                                                 const int4* __restrict__ meta_ws,
                                                 float* __restrict__ lse_ws,
                                                 _Float16* __restrict__ attn_ws) {
    __shared__ _Float16 Ksh[128 * 72];    // 18432 B; overlaid by Ph[64][136], then Pout[64][72]
    __shared__ _Float16 Vt[64 * 136];     // 17408 B
    __shared__ int4 kmeta[128];

    int xcd = blockIdx.x & 7, slot = blockIdx.x >> 3;
    int b = xcd * 2 + (slot >> 8);
    int rem = slot & 255, n = rem >> 2, r = rem & 3;
    int tid = threadIdx.x;
    int w = tid >> 6, lane = tid & 63, quad = lane >> 4, l15 = lane & 15;
    int hibase = (b * 4 + r) * L_;
    const int4* mp = meta_ws + hibase;
    int nprev = (n + 63) & 63;

    {   // stage K + publish kmeta (one meta read per thread, coalesced)
        int j = tid >> 1, dh = (tid & 1) * 32;
        int spos = (j < 64) ? (nprev * 64 + j) : (n * 64 + (j - 64));
        int4 me = mp[spos];
        if (dh == 0) kmeta[j] = me;
        const _Float16* src = khf + ((size_t)(b * L_ + me.y)) * 64 + dh;
        #pragma unroll
        for (int g = 0; g < 4; g++)
            *(f16x8*)&Ksh[j * 72 + dh + g * 8] = *(const f16x8*)(src + g * 8);
    }
    __syncthreads();   // b1: Ksh + kmeta ready

    {   // stage V^T: thread = (row-pair m, d-quarter sub); rows from kmeta
        int m = tid >> 2, sub = tid & 3;
        int y0 = kmeta[2 * m].y, y1 = kmeta[2 * m + 1].y;
        const _Float16* v0 = vhf + ((size_t)(b * L_ + y0)) * 64 + sub * 16;
        const _Float16* v1 = vhf + ((size_t)(b * L_ + y1)) * 64 + sub * 16;
        f16x8 a00 = *(const f16x8*)v0, a01 = *(const f16x8*)(v0 + 8);
        f16x8 a10 = *(const f16x8*)v1, a11 = *(const f16x8*)(v1 + 8);
        #pragma unroll
        for (int d = 0; d < 8; d++) {
            f16x2 hv = { a00[d], a10[d] };
            *(f16x2*)&Vt[(sub * 16 + d) * 136 + 2 * m] = hv;
            f16x2 hw = { a01[d], a11[d] };
            *(f16x2*)&Vt[(sub * 16 + 8 + d) * 136 + 2 * m] = hw;
        }
    }

    // A-frags from LDS: q rows ARE Ksh rows 64..127 (khf, same scaling)
    f16x8 afr[2];
    afr[0] = *(const f16x8*)&Ksh[(64 + w * 16 + l15) * 72 + quad * 8];
    afr[1] = *(const f16x8*)&Ksh[(64 + w * 16 + l15) * 72 + 32 + quad * 8];

    // QK^T (Ksh ready since b1; Vt not read until PV)
    f32x4 acc[8];
    #pragma unroll
    for (int jt = 0; jt < 8; jt++) acc[jt] = (f32x4){0.f, 0.f, 0.f, 0.f};
    __builtin_amdgcn_s_setprio(1);
    #pragma unroll
    for (int jt = 0; jt < 8; jt++) {
        #pragma unroll
        for (int kt = 0; kt < 2; kt++) {
            f16x8 bfr = *(const f16x8*)&Ksh[(jt * 16 + l15) * 72 + kt * 32 + quad * 8];
            acc[jt] = __builtin_amdgcn_mfma_f32_16x16x32_f16(afr[kt], bfr, acc[jt], 0, 0, 0);
        }
    }
    __builtin_amdgcn_s_setprio(0);

    int4 qm4[4]; int km4z[8]; float qs4[4];
    #pragma unroll
    for (int reg = 0; reg < 4; reg++) {
        qm4[reg] = kmeta[64 + w * 16 + quad * 4 + reg];
        qs4[reg] = qscale_g[(size_t)b * L_ + qm4[reg].y];
    }
    #pragma unroll
    for (int jt = 0; jt < 8; jt++) km4z[jt] = kmeta[jt * 16 + l15].z;
    __syncthreads();   // b2: all QK reads of Ksh done -> overlay Ph

    _Float16* Ph = Ksh;
    float lse_r[4], inv_r[4];
    #pragma unroll
    for (int reg = 0; reg < 4; reg++) {
        // valid k-columns form the contiguous range [lo, si); self at si.
        int lo = qm4[reg].x - (n - 1) * 64;          // bucket start in column space
        int width = w * 16 + quad * 4 + reg + 64 - lo;   // si - lo  (>= 0 always)
        int jl = l15 - lo;
        float qs = qs4[reg];
        float s[8];
        #pragma unroll
        for (int jt = 0; jt < 8; jt++) {
            float v = acc[jt][reg] * qs;
            int ju = jt * 16 + jl;                   // j - lo
            v = ((unsigned)ju < (unsigned)width) ? v : -1.4426951e9f;
            if (ju == width) v = -144269.50f;        // self: -1e5 * log2e
            s[jt] = v;
        }
        float m = s[0];
        #pragma unroll
        for (int jt = 1; jt < 8; jt++) m = fmaxf(m, s[jt]);
        #pragma unroll
        for (int off = 1; off < 16; off <<= 1) m = fmaxf(m, __shfl_xor(m, off));
        float te[8], sum = 0.f;
        #pragma unroll
        for (int jt = 0; jt < 8; jt++) { te[jt] = __builtin_amdgcn_exp2f(s[jt] - m); sum += te[jt]; }
        #pragma unroll
        for (int off = 1; off < 16; off <<= 1) sum += __shfl_xor(sum, off);
        inv_r[reg] = __builtin_amdgcn_rcpf(sum);
        lse_r[reg] = m * 0.6931472f + __logf(sum);
        int i = w * 16 + quad * 4 + reg;
        #pragma unroll
        for (int jt = 0; jt < 8; jt++) {
            int z1 = km4z[jt] ^ qm4[reg].z;
            int z2 = km4z[jt] ^ qm4[reg].w;
            int nz = __popc((z1 + 0x7f7f7f7f) & 0x80808080)
                   + __popc((z2 + 0x7f7f7f7f) & 0x80808080);
            float p = te[jt] * __builtin_amdgcn_rcpf((float)(8 - nz));
            Ph[i * 136 + jt * 16 + l15] = (_Float16)p;
        }
    }
    if (l15 == 0) {
        #pragma unroll
        for (int reg = 0; reg < 4; reg++)
            lse_ws[hibase + qm4[reg].y] = lse_r[reg];
    }
    __syncthreads();   // b3: Ph ready

    f32x4 oacc[4];
    #pragma unroll
    for (int nt = 0; nt < 4; nt++) oacc[nt] = (f32x4){0.f, 0.f, 0.f, 0.f};
    __builtin_amdgcn_s_setprio(1);
    #pragma unroll
    for (int kt = 0; kt < 4; kt++) {
        f16x8 pa = *(const f16x8*)&Ph[(w * 16 + l15) * 136 + kt * 32 + quad * 8];
        #pragma unroll
        for (int nt = 0; nt < 4; nt++) {
            f16x8 vb = *(const f16x8*)&Vt[(nt * 16 + l15) * 136 + kt * 32 + quad * 8];
            oacc[nt] = __builtin_amdgcn_mfma_f32_16x16x32_f16(pa, vb, oacc[nt], 0, 0, 0);
        }
    }
    __builtin_amdgcn_s_setprio(0);
    __syncthreads();   // b4: all PV reads of Ph/Vt done -> overlay Pout

    // transpose epilogue: stage normalized output tile in LDS [64][72]
    _Float16* Pout = Ksh;
    #pragma unroll
    for (int nt = 0; nt < 4; nt++) {
        #pragma unroll
        for (int reg = 0; reg < 4; reg++) {
            int i = w * 16 + quad * 4 + reg;
            Pout[i * 72 + nt * 16 + l15] = (_Float16)(oacc[nt][reg] * inv_r[reg]);
        }
    }
    __syncthreads();   // b5: Pout ready

    {   // 4 threads per row, two 16B stores each: each instruction's 4-lane
        // cluster covers a FULL 64B line even though rows are scattered.
        int row = tid >> 2, part = tid & 3;
        int y = kmeta[64 + row].y;
        _Float16* dst = attn_ws + ((size_t)hibase + y) * 64;
        f16x8 v0 = *(const f16x8*)&Pout[row * 72 + part * 8];
        f16x8 v1 = *(const f16x8*)&Pout[row * 72 + 32 + part * 8];
        *(f16x8*)(dst + part * 8) = v0;
        *(f16x8*)(dst + 32 + part * 8) = v1;
    }
}

// K4a: per (b,r) softmax-over-L stats of lse
__global__ __launch_bounds__(256) void k_rw(const float* __restrict__ lse_ws,
                                            float* __restrict__ rwmax,
                                            float* __restrict__ rwsum) {
    __shared__ float  red[256];
    __shared__ double redd[256];
    int br = blockIdx.x;
    const float* lp = lse_ws + (size_t)br * L_;
    int t = threadIdx.x;
    float m = -1e30f;
    for (int k = t; k < L_; k += 256) m = fmaxf(m, lp[k]);
    red[t] = m; __syncthreads();
    for (int s2 = 128; s2 > 0; s2 >>= 1) {
        if (t < s2) red[t] = fmaxf(red[t], red[t + s2]);
        __syncthreads();
    }
    float mm = red[0];
    double s = 0.0;
    for (int k = t; k < L_; k += 256) s += (double)expf(lp[k] - mm);
    redd[t] = s; __syncthreads();
    for (int s2 = 128; s2 > 0; s2 >>= 1) {
        if (t < s2) redd[t] += redd[t + s2];
        __syncthreads();
    }
    if (t == 0) { rwmax[br] = mm; rwsum[br] = (float)redd[0]; }
}

// K4b: vectorized combine — thread = (b,l, d-octet)
__global__ __launch_bounds__(256) void k_out(const _Float16* __restrict__ attn_ws,
                                             const float* __restrict__ lse_ws,
                                             const float* __restrict__ rwmax,
                                             const float* __restrict__ rwsum,
                                             float* __restrict__ out) {
    int gid = blockIdx.x * 256 + threadIdx.x;   // B*L*8
    int g = gid & 7;
    size_t row = (size_t)(gid >> 3);            // b*L + l
    int b = (int)(row >> 12), l = (int)(row & 4095);
    float o[8];
    #pragma unroll
    for (int k = 0; k < 8; k++) o[k] = 0.f;
    #pragma unroll
    for (int r = 0; r < 4; r++) {
        int br = b * 4 + r;
        float wgt = __expf(lse_ws[(size_t)br * L_ + l] - rwmax[br])
                  * __builtin_amdgcn_rcpf(rwsum[br]);
        f16x8 av = *(const f16x8*)&attn_ws[(((size_t)br * L_ + l) << 6) + g * 8];
        #pragma unroll
        for (int k = 0; k < 8; k++) o[k] += (float)av[k] * wgt;
    }
    float4* op = (float4*)(out + row * 64 + g * 8);
    op[0] = make_float4(o[0], o[1], o[2], o[3]);
    op[1] = make_float4(o[4], o[5], o[6], o[7]);
}

extern "C" void kernel_launch(void* const* d_in, const int* in_sizes, int n_in,
                              void* d_out, int out_size, void* d_ws, size_t ws_size,
                              hipStream_t stream) {
    const float* query = (const float*)d_in[0];
    const float* value = (const float*)d_in[1];
    const float* rm    = (const float*)d_in[2];
    char* ws = (char*)d_ws;
    double*    rmn    = (double*)ws;
    int*       h_ws   = (int*)(ws + ((size_t)1 << 20));
    int*       oi_ws  = (int*)(ws + ((size_t)3 << 20));
    float*     lse_ws = (float*)(ws + ((size_t)4 << 20));
    float*     rwmax  = (float*)(ws + ((size_t)5 << 20));
    float*     rwsum  = (float*)(ws + ((size_t)5 << 20) + 256);
    int*       fix_cnt= (int*)(ws + ((size_t)5 << 20) + 512);
    int*       fix_list=(int*)(ws + ((size_t)5 << 20) + 1024);
    int*       bstart = (int*)(ws + ((size_t)5 << 20) + ((size_t)256 << 10));
    _Float16*  attn_ws= (_Float16*)(ws + ((size_t)6 << 20));
    _Float16*  rhi_g  = (_Float16*)(ws + ((size_t)40 << 20));
    _Float16*  rlo_g  = (_Float16*)(ws + ((size_t)40 << 20) + ((size_t)1 << 19));
    int4*      meta_ws= (int4*)(ws + ((size_t)41 << 20));
    float*     qscale = (float*)(ws + ((size_t)45 << 20));
    _Float16*  khf    = (_Float16*)(ws + ((size_t)53 << 20));
    _Float16*  vhf    = (_Float16*)(ws + ((size_t)61 << 20));
    float*     out    = (float*)d_out;

    hipLaunchKernelGGL(k_rmnorm, dim3(2048), dim3(64),  0, stream, rm, rmn, rhi_g, rlo_g, fix_cnt);
    hipLaunchKernelGGL(k_hash,   dim3(1024), dim3(256), 0, stream, query, value, rhi_g, rlo_g,
                       h_ws, fix_cnt, fix_list, qscale, khf, vhf);
    hipLaunchKernelGGL(k_fix,    dim3(64),   dim3(64),  0, stream, query, rmn,
                       fix_cnt, fix_list, h_ws);
    hipLaunchKernelGGL(k_sort,   dim3(64),   dim3(256), 0, stream, h_ws, oi_ws, bstart);
    hipLaunchKernelGGL(k_meta,   dim3(1024), dim3(256), 0, stream, h_ws, oi_ws, bstart, meta_ws);
    hipLaunchKernelGGL(k_attn,   dim3(4096), dim3(256), 0, stream,
                       qscale, khf, vhf, meta_ws, lse_ws, attn_ws);
    hipLaunchKernelGGL(k_rw,     dim3(64),   dim3(256), 0, stream, lse_ws, rwmax, rwsum);
    hipLaunchKernelGGL(k_out,    dim3(2048), dim3(256), 0, stream,
                       attn_ws, lse_ws, rwmax, rwsum, out);
}

// Round 6
// 160.059 us; speedup vs baseline: 1.0643x; 1.0007x over previous
//
#include <hip/hip_runtime.h>
#include <math.h>

#define B_  16
#define L_  4096
#define D_  64
#define R_  4
#define NB_ 64
#define BL_ 64
#define FIXCAP 8192

typedef _Float16 f16x8 __attribute__((ext_vector_type(8)));
typedef _Float16 f16x2 __attribute__((ext_vector_type(2)));
typedef float    f32x4 __attribute__((ext_vector_type(4)));

// ---------------- ws layout ----------------
// [1MB,2MB)     h      int      [B][R][L]
// [3MB,4MB)     oi     int      [B][R][L]  original idx -> sorted pos
// [4MB,5MB)     lse    float    [B][R][L]   (original index)
// [5MB,+256)    rwmax float[64]; [+256,+512) rwsum; [+512] fix_cnt; [+1024,) fix_list
// [6MB,40MB)    attn   _Float16 [B][R][L][64]  (original index)
// [41MB,43MB)   metaA  int2     [B*R][L]   (.x=bucket_start_spos, .y=p)  per sorted pos
// [43MB,43.5MB) packA  int2     [B][L]     (.x=pack, .y=packm1) per original idx
// [45MB,+256K)  qscale float    [B][L]     ||q|| / (0.125*log2e)
// [53MB,61MB)   khf    _Float16 [B][L][64]   q/||q|| * log2e/8, f16   (log2 domain!)
// [61MB,69MB)   vhf    _Float16 [B][L][64]   v, f16
// rm layout: rm[b*8192 + d*128 + r*32 + n]

// K1: split-f16 MFMA hash + f16 tensor prep; rm normalized in-block (f32,
// matches jnp reference); deferred exact fix list.
__global__ __launch_bounds__(256, 4) void k_hash(const float* __restrict__ q,
                                                 const float* __restrict__ value,
                                                 const float* __restrict__ rm,
                                                 int* __restrict__ h_ws,
                                                 int* __restrict__ fix_cnt,
                                                 int* __restrict__ fix_list,
                                                 float* __restrict__ qscale_g,
                                                 _Float16* __restrict__ khf,
                                                 _Float16* __restrict__ vhf) {
    __shared__ __align__(16) char smem[36864];
    _Float16* Rhi = (_Float16*)smem;            // [128][72]
    _Float16* Rlo = (_Float16*)(smem + 18432);  // [128][72]
    float*    Sc  = (float*)smem;               // overlay [64][133]

    int blk = blockIdx.x;                 // b*64 + chunk
    int b = blk >> 6, chunk = blk & 63;
    int tid = threadIdx.x;
    int w = tid >> 6, lane = tid & 63, quad = lane >> 4, l15 = lane & 15;

    {   // vhf prep: 64 rows of v -> f16 (streaming, no LDS)
        int row = chunk * 64 + (tid >> 2), sub = tid & 3;
        const float4* vp = (const float4*)(value + ((size_t)(b * L_ + row)) * 64 + sub * 16);
        f16x8 h0, h1;
        #pragma unroll
        for (int c = 0; c < 2; c++) {
            float4 t0 = vp[2 * c], t1 = vp[2 * c + 1];
            f16x8& hd = c ? h1 : h0;
            hd[0]=(_Float16)t0.x; hd[1]=(_Float16)t0.y; hd[2]=(_Float16)t0.z; hd[3]=(_Float16)t0.w;
            hd[4]=(_Float16)t1.x; hd[5]=(_Float16)t1.y; hd[6]=(_Float16)t1.z; hd[7]=(_Float16)t1.w;
        }
        _Float16* dst = vhf + ((size_t)(b * L_ + row)) * 64 + sub * 16;
        *(f16x8*)dst = h0;
        *(f16x8*)(dst + 8) = h1;
    }

    {   // stage R: in-block f32 normalize of rm + hi/lo split (2 threads/row)
        int row = tid >> 1, dh2 = (tid & 1) * 32;   // row = r*32+n
        int rr = row >> 5, nn = row & 31;
        const float* rpb = rm + (size_t)b * 8192 + rr * 32 + nn;
        float ss = 0.f;
        #pragma unroll
        for (int g = 0; g < 32; g++) { float v = rpb[(dh2 + g) * 128]; ss += v * v; }
        ss += __shfl_xor(ss, 1);                    // pair (dh=0, dh=1) same wave
        float rn = 1.0f / sqrtf(ss);
        #pragma unroll
        for (int gg = 0; gg < 4; gg++) {
            f16x8 hv, lv;
            #pragma unroll
            for (int e = 0; e < 8; e++) {
                float f = rpb[(dh2 + gg * 8 + e) * 128] * rn;   // L1-hot reload
                _Float16 h = (_Float16)f;
                hv[e] = h; lv[e] = (_Float16)(f - (float)h);
            }
            *(f16x8*)&Rhi[row * 72 + dh2 + gg * 8] = hv;
            *(f16x8*)&Rlo[row * 72 + dh2 + gg * 8] = lv;
        }
    }

    int qrow = chunk * 64 + w * 16 + l15;
    const float* qp = q + ((size_t)(b * L_ + qrow)) * 64;
    float qv[16];
    #pragma unroll
    for (int kt = 0; kt < 2; kt++) {
        float4 t0 = *(const float4*)(qp + kt * 32 + quad * 8);
        float4 t1 = *(const float4*)(qp + kt * 32 + quad * 8 + 4);
        qv[8*kt+0]=t0.x; qv[8*kt+1]=t0.y; qv[8*kt+2]=t0.z; qv[8*kt+3]=t0.w;
        qv[8*kt+4]=t1.x; qv[8*kt+5]=t1.y; qv[8*kt+6]=t1.z; qv[8*kt+7]=t1.w;
    }
    f16x8 Ahi[2], Alo[2];
    #pragma unroll
    for (int kt = 0; kt < 2; kt++) {
        #pragma unroll
        for (int j = 0; j < 8; j++) {
            _Float16 hi = (_Float16)qv[8*kt+j];
            Ahi[kt][j] = hi;
            Alo[kt][j] = (_Float16)(qv[8*kt+j] - (float)hi);
        }
    }
    {   // khf (normalized, scaled f16, log2-domain) + qscale
        float ss = 0.f;
        #pragma unroll
        for (int j = 0; j < 16; j++) ss += qv[j] * qv[j];
        ss += __shfl_xor(ss, 16);
        ss += __shfl_xor(ss, 32);
        float nr = sqrtf(ss); if (nr < 1e-12f) nr = 1e-12f;
        float kscale = 0.18033688f / nr;   // c = 0.125 * log2(e)
        if (quad == 0) qscale_g[(size_t)b * L_ + qrow] = nr * 5.5451774445f;  // nr / c
        _Float16* kd = khf + ((size_t)(b * L_ + qrow)) * 64;
        #pragma unroll
        for (int kt = 0; kt < 2; kt++) {
            f16x8 hv;
            #pragma unroll
            for (int j = 0; j < 8; j++) hv[j] = (_Float16)(qv[8*kt+j] * kscale);
            *(f16x8*)(kd + kt * 32 + quad * 8) = hv;
        }
    }
    __syncthreads();

    f32x4 acc[8];
    #pragma unroll
    for (int jt = 0; jt < 8; jt++) acc[jt] = (f32x4){0.f, 0.f, 0.f, 0.f};
    #pragma unroll
    for (int jt = 0; jt < 8; jt++) {
        #pragma unroll
        for (int kt = 0; kt < 2; kt++) {
            f16x8 bh = *(const f16x8*)&Rhi[(jt * 16 + l15) * 72 + kt * 32 + quad * 8];
            f16x8 bl = *(const f16x8*)&Rlo[(jt * 16 + l15) * 72 + kt * 32 + quad * 8];
            acc[jt] = __builtin_amdgcn_mfma_f32_16x16x32_f16(Ahi[kt], bh, acc[jt], 0, 0, 0);
            acc[jt] = __builtin_amdgcn_mfma_f32_16x16x32_f16(Ahi[kt], bl, acc[jt], 0, 0, 0);
            acc[jt] = __builtin_amdgcn_mfma_f32_16x16x32_f16(Alo[kt], bh, acc[jt], 0, 0, 0);
        }
    }
    __syncthreads();

    #pragma unroll
    for (int jt = 0; jt < 8; jt++) {
        #pragma unroll
        for (int reg = 0; reg < 4; reg++)
            Sc[(w * 16 + quad * 4 + reg) * 133 + jt * 16 + l15] = acc[jt][reg];
    }
    __syncthreads();

    {
        // top-2 of |v| with sign-tagged argmax. Exact ties (|v| equal) always
        // satisfy v1-v2 < 4e-5 -> resolved by k_fix with reference tie order.
        int row = tid & 63, r = tid >> 6;
        const float* sp = &Sc[row * 133 + r * 32];
        float v1 = -1e30f, v2 = -1e30f; int i1 = 0;
        #pragma unroll
        for (int n = 0; n < 32; n++) {
            float v = sp[n];
            float a = fabsf(v);
            int cand = n | ((__float_as_uint(v) >> 26) & 32);
            if (a > v1) i1 = cand;
            v2 = __builtin_amdgcn_fmed3f(a, v1, v2);
            v1 = fmaxf(a, v1);
        }
        int l = chunk * 64 + row;
        h_ws[((size_t)(b * 4 + r)) * L_ + l] = i1;
        if (v1 - v2 < 4e-5f) {
            int slot = atomicAdd(fix_cnt, 1);
            if (slot < FIXCAP) fix_list[slot] = (b << 14) | (r << 12) | l;
        }
    }
}

// K1b: exact fp64 resolve (self-normalizing from raw rm), one wave per row.
__global__ __launch_bounds__(64) void k_fix(const float* __restrict__ q,
                                            const float* __restrict__ rm,
                                            const int* __restrict__ fix_cnt,
                                            const int* __restrict__ fix_list,
                                            int* __restrict__ h_ws) {
    int cnt = *fix_cnt; if (cnt > FIXCAP) cnt = FIXCAP;
    int lane = threadIdx.x;
    for (int i = blockIdx.x; i < cnt; i += gridDim.x) {
        int e = fix_list[i];
        int b = e >> 14, r = (e >> 12) & 3, l = e & 4095;
        int n = lane & 31;
        const float* rpb = rm + (size_t)b * 8192 + r * 32 + n;
        const float* qr = q + ((size_t)(b * L_ + l)) * 64;
        double s2 = 0.0, dot = 0.0;
        #pragma unroll 8
        for (int d = 0; d < 64; d++) {
            double m = (double)rpb[d * 128];
            s2 += m * m;
            dot += (double)qr[d] * m;
        }
        double acc = dot / sqrt(s2);
        double v = (lane < 32) ? acc : -acc;
        int idx = lane;
        #pragma unroll
        for (int off = 1; off < 64; off <<= 1) {
            double ov = __shfl_xor(v, off);
            int   oidx = __shfl_xor(idx, off);
            if (ov > v || (ov == v && oidx < idx)) { v = ov; idx = oidx; }
        }
        if (lane == 0) h_ws[((size_t)(b * 4 + r)) * L_ + l] = idx;
    }
}

// K2: stable counting sort per (b,r). Emits oi (orig->spos, coalesced) AND
// metaA (spos -> {bucket_start_spos, p}) — scatter happens in LDS, global
// stores fully coalesced (no write-allocate amplification).
__global__ __launch_bounds__(256) void k_sort(const int* __restrict__ h_ws,
                                              int* __restrict__ oi_ws,
                                              int2* __restrict__ metaA) {
    __shared__ __align__(16) unsigned short cnt[64 * 257];   // [bucket][thread]
    __shared__ __align__(16) unsigned short oi_s[256 * 17];  // padded [t][k]
    __shared__ __align__(16) unsigned short p_s[4096];       // spos -> p
    __shared__ __align__(16) unsigned short sb_s[4096];      // spos -> bucket start
    __shared__ int part[256];                                // [seg][bucket] bases
    __shared__ int bstart_s[64];

    int br = blockIdx.x;
    int t = threadIdx.x;
    const int* hp = h_ws + (size_t)br * L_;

    unsigned int* cz = (unsigned int*)cnt;
    #pragma unroll
    for (int i = 0; i < 33; i++) {
        int idx = i * 256 + t;
        if (idx < 8224) cz[idx] = 0;
    }

    int key[16];
    const int4* hp4 = (const int4*)(hp + t * 16);
    #pragma unroll
    for (int g = 0; g < 4; g++) {
        int4 v = hp4[g];
        key[g*4+0] = v.x; key[g*4+1] = v.y; key[g*4+2] = v.z; key[g*4+3] = v.w;
    }
    __syncthreads();

    #pragma unroll
    for (int k = 0; k < 16; k++) {
        unsigned short* c = &cnt[key[k] * 257 + t];
        *c = (unsigned short)(*c + 1);
    }
    __syncthreads();

    int u = t & 63, s = t >> 6;
    {
        int run = 0;
        int base_idx = u * 257 + s * 64;
        #pragma unroll 16
        for (int i = 0; i < 64; i++) {
            int c = cnt[base_idx + i];
            cnt[base_idx + i] = (unsigned short)run;
            run += c;
        }
        part[s * 64 + u] = run;
    }
    __syncthreads();

    if (t < 64) {
        int p0 = part[t], p1 = part[64 + t], p2 = part[128 + t], p3 = part[192 + t];
        int tot = p0 + p1 + p2 + p3;
        int v = tot;
        #pragma unroll
        for (int off = 1; off < 64; off <<= 1) {
            int o = __shfl_up(v, off);
            if (t >= off) v += o;
        }
        int base = v - tot;              // first spos of bucket t
        bstart_s[t] = base;
        part[t]       = base;
        part[64 + t]  = base + p0;
        part[128 + t] = base + p0 + p1;
        part[192 + t] = base + p0 + p1 + p2;
    }
    __syncthreads();

    int sbase = s * 64;
    #pragma unroll
    for (int k = 0; k < 16; k++) {
        int uk = key[k];
        unsigned short* c = &cnt[uk * 257 + t];
        int pos = part[sbase + uk] + *c;
        *c = (unsigned short)(*c + 1);
        int idx = t * 16 + k;
        oi_s[(idx >> 4) * 17 + (idx & 15)] = (unsigned short)pos;
        p_s[pos]  = (unsigned short)idx;
        sb_s[pos] = (unsigned short)bstart_s[uk];
    }
    __syncthreads();

    int* op = oi_ws + (size_t)br * L_;
    int2* mp = metaA + (size_t)br * L_;
    #pragma unroll
    for (int k = 0; k < 16; k++) {
        int e = k * 256 + t;
        op[e] = (int)oi_s[(e >> 4) * 17 + (e & 15)];
        mp[e] = make_int2((int)sb_s[e], (int)p_s[e]);
    }
}

// K2b: round-packs per ORIGINAL index (per b, shared by all 4 rounds) —
// all reads and the int2 write coalesced.
__global__ __launch_bounds__(256) void k_pack(const int* __restrict__ oi_ws,
                                              int2* __restrict__ packA) {
    int gid = blockIdx.x * 256 + threadIdx.x;   // B*L
    int b = gid >> 12, p = gid & 4095;
    int pack = 0, packm1 = 0;
    #pragma unroll
    for (int r2 = 0; r2 < 4; r2++) {
        int o = oi_ws[((size_t)(b * 4 + r2)) * L_ + p];
        int bk = o >> 6;
        pack   |= bk << (8 * r2);
        packm1 |= ((bk + 63) & 63) << (8 * r2);
    }
    packA[gid] = make_int2(pack, packm1);
}

// K3: MFMA fused attention. A-frags from Ksh rows 64..127 + qscale restore;
// range-based causal mask; exp2-domain softmax; full-line store epilogue.
// Meta = metaA (coalesced) + packA (scattered 8B, cache-hot).
__global__ __launch_bounds__(256, 4) void k_attn(const float* __restrict__ qscale_g,
                                                 const _Float16* __restrict__ khf,
                                                 const _Float16* __restrict__ vhf,
                                                 const int2* __restrict__ metaA,
                                                 const int2* __restrict__ packA,
                                                 float* __restrict__ lse_ws,
                                                 _Float16* __restrict__ attn_ws) {
    __shared__ _Float16 Ksh[128 * 72];    // 18432 B; overlaid by Ph[64][136], then Pout[64][72]
    __shared__ _Float16 Vt[64 * 136];     // 17408 B
    __shared__ int4 kmeta[128];

    int xcd = blockIdx.x & 7, slot = blockIdx.x >> 3;
    int b = xcd * 2 + (slot >> 8);
    int rem = slot & 255, n = rem >> 2, r = rem & 3;
    int tid = threadIdx.x;
    int w = tid >> 6, lane = tid & 63, quad = lane >> 4, l15 = lane & 15;
    int hibase = (b * 4 + r) * L_;
    const int2* mpA = metaA + hibase;
    int nprev = (n + 63) & 63;

    {   // stage K + publish kmeta
        int j = tid >> 1, dh = (tid & 1) * 32;
        int spos = (j < 64) ? (nprev * 64 + j) : (n * 64 + (j - 64));
        int2 ma = mpA[spos];
        const _Float16* src = khf + ((size_t)(b * L_ + ma.y)) * 64 + dh;
        f16x8 t0 = *(const f16x8*)(src);
        f16x8 t1 = *(const f16x8*)(src + 8);
        f16x8 t2 = *(const f16x8*)(src + 16);
        f16x8 t3 = *(const f16x8*)(src + 24);
        if (dh == 0) {
            int2 pk = packA[b * L_ + ma.y];
            kmeta[j] = make_int4(ma.x, ma.y, pk.x, pk.y);
        }
        *(f16x8*)&Ksh[j * 72 + dh + 0]  = t0;
        *(f16x8*)&Ksh[j * 72 + dh + 8]  = t1;
        *(f16x8*)&Ksh[j * 72 + dh + 16] = t2;
        *(f16x8*)&Ksh[j * 72 + dh + 24] = t3;
    }
    __syncthreads();   // b1: Ksh + kmeta ready

    {   // stage V^T: thread = (row-pair m, d-quarter sub); rows from kmeta
        int m = tid >> 2, sub = tid & 3;
        int y0 = kmeta[2 * m].y, y1 = kmeta[2 * m + 1].y;
        const _Float16* v0 = vhf + ((size_t)(b * L_ + y0)) * 64 + sub * 16;
        const _Float16* v1 = vhf + ((size_t)(b * L_ + y1)) * 64 + sub * 16;
        f16x8 a00 = *(const f16x8*)v0, a01 = *(const f16x8*)(v0 + 8);
        f16x8 a10 = *(const f16x8*)v1, a11 = *(const f16x8*)(v1 + 8);
        #pragma unroll
        for (int d = 0; d < 8; d++) {
            f16x2 hv = { a00[d], a10[d] };
            *(f16x2*)&Vt[(sub * 16 + d) * 136 + 2 * m] = hv;
            f16x2 hw = { a01[d], a11[d] };
            *(f16x2*)&Vt[(sub * 16 + 8 + d) * 136 + 2 * m] = hw;
        }
    }

    // A-frags from LDS: q rows ARE Ksh rows 64..127 (khf, same scaling)
    f16x8 afr[2];
    afr[0] = *(const f16x8*)&Ksh[(64 + w * 16 + l15) * 72 + quad * 8];
    afr[1] = *(const f16x8*)&Ksh[(64 + w * 16 + l15) * 72 + 32 + quad * 8];

    // hoisted meta/scale loads — latency hides under the QK MFMA cluster
    int4 qm4[4]; int km4z[8]; float qs4[4];
    #pragma unroll
    for (int reg = 0; reg < 4; reg++) {
        qm4[reg] = kmeta[64 + w * 16 + quad * 4 + reg];
        qs4[reg] = qscale_g[(size_t)b * L_ + qm4[reg].y];
    }
    #pragma unroll
    for (int jt = 0; jt < 8; jt++) km4z[jt] = kmeta[jt * 16 + l15].z;

    // QK^T
    f32x4 acc[8];
    #pragma unroll
    for (int jt = 0; jt < 8; jt++) acc[jt] = (f32x4){0.f, 0.f, 0.f, 0.f};
    __builtin_amdgcn_s_setprio(1);
    #pragma unroll
    for (int jt = 0; jt < 8; jt++) {
        #pragma unroll
        for (int kt = 0; kt < 2; kt++) {
            f16x8 bfr = *(const f16x8*)&Ksh[(jt * 16 + l15) * 72 + kt * 32 + quad * 8];
            acc[jt] = __builtin_amdgcn_mfma_f32_16x16x32_f16(afr[kt], bfr, acc[jt], 0, 0, 0);
        }
    }
    __builtin_amdgcn_s_setprio(0);
    __syncthreads();   // b2: all QK reads of Ksh done -> overlay Ph

    _Float16* Ph = Ksh;
    float lse_r[4], inv_r[4];
    #pragma unroll
    for (int reg = 0; reg < 4; reg++) {
        // valid k-columns form the contiguous range [lo, si); self at si.
        int lo = qm4[reg].x - (n - 1) * 64;          // bucket start in column space
        int width = w * 16 + quad * 4 + reg + 64 - lo;   // si - lo
        int jl = l15 - lo;
        float qs = qs4[reg];
        float s[8];
        #pragma unroll
        for (int jt = 0; jt < 8; jt++) {
            float v = acc[jt][reg] * qs;
            int ju = jt * 16 + jl;                   // j - lo
            v = ((unsigned)ju < (unsigned)width) ? v : -1.4426951e9f;
            if (ju == width) v = -144269.50f;        // self: -1e5 * log2e
            s[jt] = v;
        }
        float m = s[0];
        #pragma unroll
        for (int jt = 1; jt < 8; jt++) m = fmaxf(m, s[jt]);
        #pragma unroll
        for (int off = 1; off < 16; off <<= 1) m = fmaxf(m, __shfl_xor(m, off));
        float te[8], sum = 0.f;
        #pragma unroll
        for (int jt = 0; jt < 8; jt++) { te[jt] = __builtin_amdgcn_exp2f(s[jt] - m); sum += te[jt]; }
        #pragma unroll
        for (int off = 1; off < 16; off <<= 1) sum += __shfl_xor(sum, off);
        inv_r[reg] = __builtin_amdgcn_rcpf(sum);
        lse_r[reg] = m * 0.6931472f + __logf(sum);
        int i = w * 16 + quad * 4 + reg;
        #pragma unroll
        for (int jt = 0; jt < 8; jt++) {
            int z1 = km4z[jt] ^ qm4[reg].z;
            int z2 = km4z[jt] ^ qm4[reg].w;
            int nz = __popc((z1 + 0x7f7f7f7f) & 0x80808080)
                   + __popc((z2 + 0x7f7f7f7f) & 0x80808080);
            float p = te[jt] * __builtin_amdgcn_rcpf((float)(8 - nz));
            Ph[i * 136 + jt * 16 + l15] = (_Float16)p;
        }
    }
    if (l15 == 0) {
        #pragma unroll
        for (int reg = 0; reg < 4; reg++)
            lse_ws[hibase + qm4[reg].y] = lse_r[reg];
    }
    __syncthreads();   // b3: Ph ready

    f32x4 oacc[4];
    #pragma unroll
    for (int nt = 0; nt < 4; nt++) oacc[nt] = (f32x4){0.f, 0.f, 0.f, 0.f};
    __builtin_amdgcn_s_setprio(1);
    #pragma unroll
    for (int kt = 0; kt < 4; kt++) {
        f16x8 pa = *(const f16x8*)&Ph[(w * 16 + l15) * 136 + kt * 32 + quad * 8];
        #pragma unroll
        for (int nt = 0; nt < 4; nt++) {
            f16x8 vb = *(const f16x8*)&Vt[(nt * 16 + l15) * 136 + kt * 32 + quad * 8];
            oacc[nt] = __builtin_amdgcn_mfma_f32_16x16x32_f16(pa, vb, oacc[nt], 0, 0, 0);
        }
    }
    __builtin_amdgcn_s_setprio(0);
    __syncthreads();   // b4: all PV reads done -> overlay Pout

    _Float16* Pout = Ksh;
    #pragma unroll
    for (int nt = 0; nt < 4; nt++) {
        #pragma unroll
        for (int reg = 0; reg < 4; reg++) {
            int i = w * 16 + quad * 4 + reg;
            Pout[i * 72 + nt * 16 + l15] = (_Float16)(oacc[nt][reg] * inv_r[reg]);
        }
    }
    __syncthreads();   // b5: Pout ready

    {   // 4 threads/row, two 16B stores each: full 64B lines despite row scatter
        int row = tid >> 2, part = tid & 3;
        int y = kmeta[64 + row].y;
        _Float16* dst = attn_ws + ((size_t)hibase + y) * 64;
        f16x8 v0 = *(const f16x8*)&Pout[row * 72 + part * 8];
        f16x8 v1 = *(const f16x8*)&Pout[row * 72 + 32 + part * 8];
        *(f16x8*)(dst + part * 8) = v0;
        *(f16x8*)(dst + 32 + part * 8) = v1;
    }
}

// K4a: per (b,r) softmax-over-L stats of lse
__global__ __launch_bounds__(256) void k_rw(const float* __restrict__ lse_ws,
                                            float* __restrict__ rwmax,
                                            float* __restrict__ rwsum) {
    __shared__ float  red[256];
    __shared__ double redd[256];
    int br = blockIdx.x;
    const float* lp = lse_ws + (size_t)br * L_;
    int t = threadIdx.x;
    float m = -1e30f;
    for (int k = t; k < L_; k += 256) m = fmaxf(m, lp[k]);
    red[t] = m; __syncthreads();
    for (int s2 = 128; s2 > 0; s2 >>= 1) {
        if (t < s2) red[t] = fmaxf(red[t], red[t + s2]);
        __syncthreads();
    }
    float mm = red[0];
    double s = 0.0;
    for (int k = t; k < L_; k += 256) s += (double)expf(lp[k] - mm);
    redd[t] = s; __syncthreads();
    for (int s2 = 128; s2 > 0; s2 >>= 1) {
        if (t < s2) redd[t] += redd[t + s2];
        __syncthreads();
    }
    if (t == 0) { rwmax[br] = mm; rwsum[br] = (float)redd[0]; }
}

// K4b: vectorized combine — thread = (b,l, d-octet)
__global__ __launch_bounds__(256) void k_out(const _Float16* __restrict__ attn_ws,
                                             const float* __restrict__ lse_ws,
                                             const float* __restrict__ rwmax,
                                             const float* __restrict__ rwsum,
                                             float* __restrict__ out) {
    int gid = blockIdx.x * 256 + threadIdx.x;   // B*L*8
    int g = gid & 7;
    size_t row = (size_t)(gid >> 3);            // b*L + l
    int b = (int)(row >> 12), l = (int)(row & 4095);
    float o[8];
    #pragma unroll
    for (int k = 0; k < 8; k++) o[k] = 0.f;
    #pragma unroll
    for (int r = 0; r < 4; r++) {
        int br = b * 4 + r;
        float wgt = __expf(lse_ws[(size_t)br * L_ + l] - rwmax[br])
                  * __builtin_amdgcn_rcpf(rwsum[br]);
        f16x8 av = *(const f16x8*)&attn_ws[(((size_t)br * L_ + l) << 6) + g * 8];
        #pragma unroll
        for (int k = 0; k < 8; k++) o[k] += (float)av[k] * wgt;
    }
    float4* op = (float4*)(out + row * 64 + g * 8);
    op[0] = make_float4(o[0], o[1], o[2], o[3]);
    op[1] = make_float4(o[4], o[5], o[6], o[7]);
}

extern "C" void kernel_launch(void* const* d_in, const int* in_sizes, int n_in,
                              void* d_out, int out_size, void* d_ws, size_t ws_size,
                              hipStream_t stream) {
    const float* query = (const float*)d_in[0];
    const float* value = (const float*)d_in[1];
    const float* rm    = (const float*)d_in[2];
    char* ws = (char*)d_ws;
    int*       h_ws   = (int*)(ws + ((size_t)1 << 20));
    int*       oi_ws  = (int*)(ws + ((size_t)3 << 20));
    float*     lse_ws = (float*)(ws + ((size_t)4 << 20));
    float*     rwmax  = (float*)(ws + ((size_t)5 << 20));
    float*     rwsum  = (float*)(ws + ((size_t)5 << 20) + 256);
    int*       fix_cnt= (int*)(ws + ((size_t)5 << 20) + 512);
    int*       fix_list=(int*)(ws + ((size_t)5 << 20) + 1024);
    _Float16*  attn_ws= (_Float16*)(ws + ((size_t)6 << 20));
    int2*      metaA  = (int2*)(ws + ((size_t)41 << 20));
    int2*      packA  = (int2*)(ws + ((size_t)43 << 20));
    float*     qscale = (float*)(ws + ((size_t)45 << 20));
    _Float16*  khf    = (_Float16*)(ws + ((size_t)53 << 20));
    _Float16*  vhf    = (_Float16*)(ws + ((size_t)61 << 20));
    float*     out    = (float*)d_out;

    hipMemsetAsync(fix_cnt, 0, sizeof(int), stream);
    hipLaunchKernelGGL(k_hash,   dim3(1024), dim3(256), 0, stream, query, value, rm,
                       h_ws, fix_cnt, fix_list, qscale, khf, vhf);
    hipLaunchKernelGGL(k_fix,    dim3(64),   dim3(64),  0, stream, query, rm,
                       fix_cnt, fix_list, h_ws);
    hipLaunchKernelGGL(k_sort,   dim3(64),   dim3(256), 0, stream, h_ws, oi_ws, metaA);
    hipLaunchKernelGGL(k_pack,   dim3(256),  dim3(256), 0, stream, oi_ws, packA);
    hipLaunchKernelGGL(k_attn,   dim3(4096), dim3(256), 0, stream,
                       qscale, khf, vhf, metaA, packA, lse_ws, attn_ws);
    hipLaunchKernelGGL(k_rw,     dim3(64),   dim3(256), 0, stream, lse_ws, rwmax, rwsum);
    hipLaunchKernelGGL(k_out,    dim3(2048), dim3(256), 0, stream,
                       attn_ws, lse_ws, rwmax, rwsum, out);
}

// Round 7
// 156.001 us; speedup vs baseline: 1.0920x; 1.0260x over previous
//
#include <hip/hip_runtime.h>
#include <math.h>

#define B_  16
#define L_  4096
#define D_  64
#define R_  4
#define NB_ 64
#define BL_ 64

typedef _Float16 f16x8 __attribute__((ext_vector_type(8)));
typedef _Float16 f16x2 __attribute__((ext_vector_type(2)));
typedef float    f32x4 __attribute__((ext_vector_type(4)));

// ---------------- ws layout ----------------
// [1MB,2MB)     h      int      [B][R][L]   (bit30 = ambiguous flag)
// [4MB,5MB)     lse    float    [B][R][L]   (original index)
// [5MB,+256)    rwmax float[64]; [+256,+512) rwsum
// [6MB,40MB)    attn   _Float16 [B][R][L][64]  (original index)
// [41MB,43MB)   metaA  int2     [B*R][L]   (.x=bucket_start_spos, .y=p)  per sorted pos
// [43MB,+256K)  packB  u8       [B][L][4]  bk byte per round, per original idx
// [45MB,+256K)  qscale float    [B][L]     ||q|| / (0.125*log2e)
// [53MB,61MB)   khf    _Float16 [B][L][64]   q/||q|| * log2e/8, f16   (log2 domain!)
// [61MB,69MB)   vhf    _Float16 [B][L][64]   v, f16
// rm layout: rm[b*8192 + d*128 + r*32 + n]

// K1: split-f16 MFMA hash + f16 tensor prep; rm normalized in-block (f32);
// ambiguous rows flagged via bit30 of h (resolved exactly inside k_sort).
__global__ __launch_bounds__(256, 4) void k_hash(const float* __restrict__ q,
                                                 const float* __restrict__ value,
                                                 const float* __restrict__ rm,
                                                 int* __restrict__ h_ws,
                                                 float* __restrict__ qscale_g,
                                                 _Float16* __restrict__ khf,
                                                 _Float16* __restrict__ vhf) {
    __shared__ __align__(16) char smem[36864];
    _Float16* Rhi = (_Float16*)smem;            // [128][72]
    _Float16* Rlo = (_Float16*)(smem + 18432);  // [128][72]
    float*    Sc  = (float*)smem;               // overlay [64][133]

    int blk = blockIdx.x;                 // b*64 + chunk
    int b = blk >> 6, chunk = blk & 63;
    int tid = threadIdx.x;
    int w = tid >> 6, lane = tid & 63, quad = lane >> 4, l15 = lane & 15;

    {   // vhf prep: 64 rows of v -> f16 (streaming, no LDS)
        int row = chunk * 64 + (tid >> 2), sub = tid & 3;
        const float4* vp = (const float4*)(value + ((size_t)(b * L_ + row)) * 64 + sub * 16);
        f16x8 h0, h1;
        #pragma unroll
        for (int c = 0; c < 2; c++) {
            float4 t0 = vp[2 * c], t1 = vp[2 * c + 1];
            f16x8& hd = c ? h1 : h0;
            hd[0]=(_Float16)t0.x; hd[1]=(_Float16)t0.y; hd[2]=(_Float16)t0.z; hd[3]=(_Float16)t0.w;
            hd[4]=(_Float16)t1.x; hd[5]=(_Float16)t1.y; hd[6]=(_Float16)t1.z; hd[7]=(_Float16)t1.w;
        }
        _Float16* dst = vhf + ((size_t)(b * L_ + row)) * 64 + sub * 16;
        *(f16x8*)dst = h0;
        *(f16x8*)(dst + 8) = h1;
    }

    {   // stage R: in-block f32 normalize of rm + hi/lo split (2 threads/row)
        int row = tid >> 1, dh2 = (tid & 1) * 32;   // row = r*32+n
        int rr = row >> 5, nn = row & 31;
        const float* rpb = rm + (size_t)b * 8192 + rr * 32 + nn;
        float ss = 0.f;
        #pragma unroll
        for (int g = 0; g < 32; g++) { float v = rpb[(dh2 + g) * 128]; ss += v * v; }
        ss += __shfl_xor(ss, 1);                    // pair (dh=0, dh=1) same wave
        float rn = 1.0f / sqrtf(ss);
        #pragma unroll
        for (int gg = 0; gg < 4; gg++) {
            f16x8 hv, lv;
            #pragma unroll
            for (int e = 0; e < 8; e++) {
                float f = rpb[(dh2 + gg * 8 + e) * 128] * rn;   // L1-hot reload
                _Float16 h = (_Float16)f;
                hv[e] = h; lv[e] = (_Float16)(f - (float)h);
            }
            *(f16x8*)&Rhi[row * 72 + dh2 + gg * 8] = hv;
            *(f16x8*)&Rlo[row * 72 + dh2 + gg * 8] = lv;
        }
    }

    int qrow = chunk * 64 + w * 16 + l15;
    const float* qp = q + ((size_t)(b * L_ + qrow)) * 64;
    float qv[16];
    #pragma unroll
    for (int kt = 0; kt < 2; kt++) {
        float4 t0 = *(const float4*)(qp + kt * 32 + quad * 8);
        float4 t1 = *(const float4*)(qp + kt * 32 + quad * 8 + 4);
        qv[8*kt+0]=t0.x; qv[8*kt+1]=t0.y; qv[8*kt+2]=t0.z; qv[8*kt+3]=t0.w;
        qv[8*kt+4]=t1.x; qv[8*kt+5]=t1.y; qv[8*kt+6]=t1.z; qv[8*kt+7]=t1.w;
    }
    f16x8 Ahi[2], Alo[2];
    #pragma unroll
    for (int kt = 0; kt < 2; kt++) {
        #pragma unroll
        for (int j = 0; j < 8; j++) {
            _Float16 hi = (_Float16)qv[8*kt+j];
            Ahi[kt][j] = hi;
            Alo[kt][j] = (_Float16)(qv[8*kt+j] - (float)hi);
        }
    }
    {   // khf (normalized, scaled f16, log2-domain) + qscale
        float ss = 0.f;
        #pragma unroll
        for (int j = 0; j < 16; j++) ss += qv[j] * qv[j];
        ss += __shfl_xor(ss, 16);
        ss += __shfl_xor(ss, 32);
        float nr = sqrtf(ss); if (nr < 1e-12f) nr = 1e-12f;
        float kscale = 0.18033688f / nr;   // c = 0.125 * log2(e)
        if (quad == 0) qscale_g[(size_t)b * L_ + qrow] = nr * 5.5451774445f;  // nr / c
        _Float16* kd = khf + ((size_t)(b * L_ + qrow)) * 64;
        #pragma unroll
        for (int kt = 0; kt < 2; kt++) {
            f16x8 hv;
            #pragma unroll
            for (int j = 0; j < 8; j++) hv[j] = (_Float16)(qv[8*kt+j] * kscale);
            *(f16x8*)(kd + kt * 32 + quad * 8) = hv;
        }
    }
    __syncthreads();

    f32x4 acc[8];
    #pragma unroll
    for (int jt = 0; jt < 8; jt++) acc[jt] = (f32x4){0.f, 0.f, 0.f, 0.f};
    #pragma unroll
    for (int jt = 0; jt < 8; jt++) {
        #pragma unroll
        for (int kt = 0; kt < 2; kt++) {
            f16x8 bh = *(const f16x8*)&Rhi[(jt * 16 + l15) * 72 + kt * 32 + quad * 8];
            f16x8 bl = *(const f16x8*)&Rlo[(jt * 16 + l15) * 72 + kt * 32 + quad * 8];
            acc[jt] = __builtin_amdgcn_mfma_f32_16x16x32_f16(Ahi[kt], bh, acc[jt], 0, 0, 0);
            acc[jt] = __builtin_amdgcn_mfma_f32_16x16x32_f16(Ahi[kt], bl, acc[jt], 0, 0, 0);
            acc[jt] = __builtin_amdgcn_mfma_f32_16x16x32_f16(Alo[kt], bh, acc[jt], 0, 0, 0);
        }
    }
    __syncthreads();

    #pragma unroll
    for (int jt = 0; jt < 8; jt++) {
        #pragma unroll
        for (int reg = 0; reg < 4; reg++)
            Sc[(w * 16 + quad * 4 + reg) * 133 + jt * 16 + l15] = acc[jt][reg];
    }
    __syncthreads();

    {
        // top-2 of |v| with sign-tagged argmax. Ambiguous (v1-v2 < 4e-5):
        // flag bit30; k_sort resolves exactly with reference tie order.
        int row = tid & 63, r = tid >> 6;
        const float* sp = &Sc[row * 133 + r * 32];
        float v1 = -1e30f, v2 = -1e30f; int i1 = 0;
        #pragma unroll
        for (int n = 0; n < 32; n++) {
            float v = sp[n];
            float a = fabsf(v);
            int cand = n | ((__float_as_uint(v) >> 26) & 32);
            if (a > v1) i1 = cand;
            v2 = __builtin_amdgcn_fmed3f(a, v1, v2);
            v1 = fmaxf(a, v1);
        }
        int l = chunk * 64 + row;
        if (v1 - v2 < 4e-5f) i1 |= (1 << 30);
        h_ws[((size_t)(b * 4 + r)) * L_ + l] = i1;
    }
}

// K2: fused exact-fix + stable counting sort per (b,r).
// Emits metaA (spos -> {bucket_start, p}, coalesced) and this round's bk byte
// of packB (per original idx). All scatters stay in LDS.
__global__ __launch_bounds__(256) void k_sort(const int* __restrict__ h_ws,
                                              const float* __restrict__ q,
                                              const float* __restrict__ rm,
                                              int2* __restrict__ metaA,
                                              unsigned char* __restrict__ packB) {
    __shared__ __align__(16) unsigned short cnt[64 * 257];   // [bucket][thread]
    __shared__ __align__(16) unsigned short oi_s[256 * 17];  // padded [t][k]: orig->pos
    __shared__ __align__(16) unsigned short p_s[4096];       // fixmap, then spos->p
    __shared__ __align__(16) unsigned short sb_s[4096];      // fixlist, then spos->bstart
    __shared__ int part[256];                                // [seg][bucket] bases
    __shared__ int bstart_s[64];
    __shared__ int flcnt;

    int br = blockIdx.x;
    int b = br >> 2, r = br & 3;
    int t = threadIdx.x;
    const int* hp = h_ws + (size_t)br * L_;

    if (t == 0) flcnt = 0;

    // load keys (coalesced int4), strip + remember flags
    int key[16]; unsigned fmask = 0;
    const int4* hp4 = (const int4*)(hp + t * 16);
    #pragma unroll
    for (int g = 0; g < 4; g++) {
        int4 v = hp4[g];
        int raw[4] = { v.x, v.y, v.z, v.w };
        #pragma unroll
        for (int j = 0; j < 4; j++) {
            int k = g * 4 + j;
            key[k] = raw[j] & 63;
            if (raw[j] & (1 << 30)) fmask |= 1u << k;
        }
    }
    __syncthreads();   // flcnt=0 visible

    if (fmask) {
        #pragma unroll
        for (int k = 0; k < 16; k++)
            if (fmask & (1u << k)) {
                int slot = atomicAdd(&flcnt, 1);
                sb_s[slot] = (unsigned short)(t * 16 + k);   // row l (<=4096 entries)
            }
    }
    __syncthreads();

    {   // wave-cooperative exact fp64 resolve (reference tie order)
        int wid = t >> 6, lane = t & 63;
        int fc = flcnt;
        for (int e = wid; e < fc; e += 4) {
            int l = sb_s[e];
            int n = lane & 31;
            const float* rpb = rm + (size_t)b * 8192 + r * 32 + n;
            const float* qr = q + ((size_t)(b * L_ + l)) * 64;
            double s2 = 0.0, dot = 0.0;
            for (int d = 0; d < 64; d++) {
                double m = (double)rpb[d * 128];
                s2 += m * m;
                dot += (double)qr[d] * m;
            }
            double acc = dot / sqrt(s2);
            double v = (lane < 32) ? acc : -acc;
            int idx = lane;
            #pragma unroll
            for (int off = 1; off < 64; off <<= 1) {
                double ov = __shfl_xor(v, off);
                int   oidx = __shfl_xor(idx, off);
                if (ov > v || (ov == v && oidx < idx)) { v = ov; idx = oidx; }
            }
            if (lane == 0) p_s[l] = (unsigned short)idx;
        }
    }
    __syncthreads();
    if (fmask) {
        #pragma unroll
        for (int k = 0; k < 16; k++)
            if (fmask & (1u << k)) key[k] = p_s[t * 16 + k];
    }

    // zero histogram (16448 u16 = 8224 u32)
    unsigned int* cz = (unsigned int*)cnt;
    #pragma unroll
    for (int i = 0; i < 33; i++) {
        int idx = i * 256 + t;
        if (idx < 8224) cz[idx] = 0;
    }
    __syncthreads();

    // per-thread histogram
    #pragma unroll
    for (int k = 0; k < 16; k++) {
        unsigned short* c = &cnt[key[k] * 257 + t];
        *c = (unsigned short)(*c + 1);
    }
    __syncthreads();

    // within-segment exclusive prefix
    int u = t & 63, s = t >> 6;
    {
        int run = 0;
        int base_idx = u * 257 + s * 64;
        #pragma unroll 16
        for (int i = 0; i < 64; i++) {
            int c = cnt[base_idx + i];
            cnt[base_idx + i] = (unsigned short)run;
            run += c;
        }
        part[s * 64 + u] = run;
    }
    __syncthreads();

    if (t < 64) {
        int p0 = part[t], p1 = part[64 + t], p2 = part[128 + t], p3 = part[192 + t];
        int tot = p0 + p1 + p2 + p3;
        int v = tot;
        #pragma unroll
        for (int off = 1; off < 64; off <<= 1) {
            int o = __shfl_up(v, off);
            if (t >= off) v += o;
        }
        int base = v - tot;              // first spos of bucket t
        bstart_s[t] = base;
        part[t]       = base;
        part[64 + t]  = base + p0;
        part[128 + t] = base + p0 + p1;
        part[192 + t] = base + p0 + p1 + p2;
    }
    __syncthreads();

    // scatter: pos = bucket/segment base + within-segment offset (stable)
    int sbase = s * 64;
    #pragma unroll
    for (int k = 0; k < 16; k++) {
        int uk = key[k];
        unsigned short* c = &cnt[uk * 257 + t];
        int pos = part[sbase + uk] + *c;
        *c = (unsigned short)(*c + 1);
        int idx = t * 16 + k;
        oi_s[(idx >> 4) * 17 + (idx & 15)] = (unsigned short)pos;
        p_s[pos]  = (unsigned short)idx;
        sb_s[pos] = (unsigned short)bstart_s[uk];
    }
    __syncthreads();

    // coalesced outputs: metaA (int2 per spos) + this round's bk byte per orig idx
    int2* mp = metaA + (size_t)br * L_;
    unsigned char* pb = packB + ((size_t)b * L_) * 4 + r;
    #pragma unroll
    for (int k = 0; k < 16; k++) {
        int e = k * 256 + t;
        mp[e] = make_int2((int)sb_s[e], (int)p_s[e]);
        int pos = (int)oi_s[(e >> 4) * 17 + (e & 15)];
        pb[(size_t)e * 4] = (unsigned char)(pos >> 6);
    }
}

// K3: MFMA fused attention. A-frags from Ksh rows 64..127 + qscale restore;
// range-based causal mask; exp2-domain softmax; full-line store epilogue.
// packm1 derived bytewise from pack (no second table).
__global__ __launch_bounds__(256, 4) void k_attn(const float* __restrict__ qscale_g,
                                                 const _Float16* __restrict__ khf,
                                                 const _Float16* __restrict__ vhf,
                                                 const int2* __restrict__ metaA,
                                                 const unsigned int* __restrict__ packA,
                                                 float* __restrict__ lse_ws,
                                                 _Float16* __restrict__ attn_ws) {
    __shared__ _Float16 Ksh[128 * 72];    // 18432 B; overlaid by Ph[64][136], then Pout[64][72]
    __shared__ _Float16 Vt[64 * 136];     // 17408 B
    __shared__ int4 kmeta[128];

    int xcd = blockIdx.x & 7, slot = blockIdx.x >> 3;
    int b = xcd * 2 + (slot >> 8);
    int rem = slot & 255, n = rem >> 2, r = rem & 3;
    int tid = threadIdx.x;
    int w = tid >> 6, lane = tid & 63, quad = lane >> 4, l15 = lane & 15;
    int hibase = (b * 4 + r) * L_;
    const int2* mpA = metaA + hibase;
    int nprev = (n + 63) & 63;

    {   // stage K + publish kmeta
        int j = tid >> 1, dh = (tid & 1) * 32;
        int spos = (j < 64) ? (nprev * 64 + j) : (n * 64 + (j - 64));
        int2 ma = mpA[spos];
        const _Float16* src = khf + ((size_t)(b * L_ + ma.y)) * 64 + dh;
        f16x8 t0 = *(const f16x8*)(src);
        f16x8 t1 = *(const f16x8*)(src + 8);
        f16x8 t2 = *(const f16x8*)(src + 16);
        f16x8 t3 = *(const f16x8*)(src + 24);
        if (dh == 0) {
            unsigned int pk = packA[b * L_ + ma.y];
            unsigned int pm1 = ((pk | 0x40404040u) - 0x01010101u) & 0x3f3f3f3fu;
            kmeta[j] = make_int4(ma.x, ma.y, (int)pk, (int)pm1);
        }
        *(f16x8*)&Ksh[j * 72 + dh + 0]  = t0;
        *(f16x8*)&Ksh[j * 72 + dh + 8]  = t1;
        *(f16x8*)&Ksh[j * 72 + dh + 16] = t2;
        *(f16x8*)&Ksh[j * 72 + dh + 24] = t3;
    }
    __syncthreads();   // b1: Ksh + kmeta ready

    {   // stage V^T: thread = (row-pair m, d-quarter sub); rows from kmeta
        int m = tid >> 2, sub = tid & 3;
        int y0 = kmeta[2 * m].y, y1 = kmeta[2 * m + 1].y;
        const _Float16* v0 = vhf + ((size_t)(b * L_ + y0)) * 64 + sub * 16;
        const _Float16* v1 = vhf + ((size_t)(b * L_ + y1)) * 64 + sub * 16;
        f16x8 a00 = *(const f16x8*)v0, a01 = *(const f16x8*)(v0 + 8);
        f16x8 a10 = *(const f16x8*)v1, a11 = *(const f16x8*)(v1 + 8);
        #pragma unroll
        for (int d = 0; d < 8; d++) {
            f16x2 hv = { a00[d], a10[d] };
            *(f16x2*)&Vt[(sub * 16 + d) * 136 + 2 * m] = hv;
            f16x2 hw = { a01[d], a11[d] };
            *(f16x2*)&Vt[(sub * 16 + 8 + d) * 136 + 2 * m] = hw;
        }
    }

    // A-frags from LDS: q rows ARE Ksh rows 64..127 (khf, same scaling)
    f16x8 afr[2];
    afr[0] = *(const f16x8*)&Ksh[(64 + w * 16 + l15) * 72 + quad * 8];
    afr[1] = *(const f16x8*)&Ksh[(64 + w * 16 + l15) * 72 + 32 + quad * 8];

    // hoisted meta/scale loads — latency hides under the QK MFMA cluster
    int4 qm4[4]; int km4z[8]; float qs4[4];
    #pragma unroll
    for (int reg = 0; reg < 4; reg++) {
        qm4[reg] = kmeta[64 + w * 16 + quad * 4 + reg];
        qs4[reg] = qscale_g[(size_t)b * L_ + qm4[reg].y];
    }
    #pragma unroll
    for (int jt = 0; jt < 8; jt++) km4z[jt] = kmeta[jt * 16 + l15].z;

    // QK^T
    f32x4 acc[8];
    #pragma unroll
    for (int jt = 0; jt < 8; jt++) acc[jt] = (f32x4){0.f, 0.f, 0.f, 0.f};
    __builtin_amdgcn_s_setprio(1);
    #pragma unroll
    for (int jt = 0; jt < 8; jt++) {
        #pragma unroll
        for (int kt = 0; kt < 2; kt++) {
            f16x8 bfr = *(const f16x8*)&Ksh[(jt * 16 + l15) * 72 + kt * 32 + quad * 8];
            acc[jt] = __builtin_amdgcn_mfma_f32_16x16x32_f16(afr[kt], bfr, acc[jt], 0, 0, 0);
        }
    }
    __builtin_amdgcn_s_setprio(0);
    __syncthreads();   // b2: all QK reads of Ksh done -> overlay Ph

    _Float16* Ph = Ksh;
    float lse_r[4], inv_r[4];
    #pragma unroll
    for (int reg = 0; reg < 4; reg++) {
        // valid k-columns form the contiguous range [lo, si); self at si.
        int lo = qm4[reg].x - (n - 1) * 64;          // bucket start in column space
        int width = w * 16 + quad * 4 + reg + 64 - lo;   // si - lo
        int jl = l15 - lo;
        float qs = qs4[reg];
        float s[8];
        #pragma unroll
        for (int jt = 0; jt < 8; jt++) {
            float v = acc[jt][reg] * qs;
            int ju = jt * 16 + jl;                   // j - lo
            v = ((unsigned)ju < (unsigned)width) ? v : -1.4426951e9f;
            if (ju == width) v = -144269.50f;        // self: -1e5 * log2e
            s[jt] = v;
        }
        float m = s[0];
        #pragma unroll
        for (int jt = 1; jt < 8; jt++) m = fmaxf(m, s[jt]);
        #pragma unroll
        for (int off = 1; off < 16; off <<= 1) m = fmaxf(m, __shfl_xor(m, off));
        float te[8], sum = 0.f;
        #pragma unroll
        for (int jt = 0; jt < 8; jt++) { te[jt] = __builtin_amdgcn_exp2f(s[jt] - m); sum += te[jt]; }
        #pragma unroll
        for (int off = 1; off < 16; off <<= 1) sum += __shfl_xor(sum, off);
        inv_r[reg] = __builtin_amdgcn_rcpf(sum);
        lse_r[reg] = m * 0.6931472f + __logf(sum);
        int i = w * 16 + quad * 4 + reg;
        #pragma unroll
        for (int jt = 0; jt < 8; jt++) {
            int z1 = km4z[jt] ^ qm4[reg].z;
            int z2 = km4z[jt] ^ qm4[reg].w;
            int nz = __popc((z1 + 0x7f7f7f7f) & 0x80808080)
                   + __popc((z2 + 0x7f7f7f7f) & 0x80808080);
            float p = te[jt] * __builtin_amdgcn_rcpf((float)(8 - nz));
            Ph[i * 136 + jt * 16 + l15] = (_Float16)p;
        }
    }
    if (l15 == 0) {
        #pragma unroll
        for (int reg = 0; reg < 4; reg++)
            lse_ws[hibase + qm4[reg].y] = lse_r[reg];
    }
    __syncthreads();   // b3: Ph ready

    f32x4 oacc[4];
    #pragma unroll
    for (int nt = 0; nt < 4; nt++) oacc[nt] = (f32x4){0.f, 0.f, 0.f, 0.f};
    __builtin_amdgcn_s_setprio(1);
    #pragma unroll
    for (int kt = 0; kt < 4; kt++) {
        f16x8 pa = *(const f16x8*)&Ph[(w * 16 + l15) * 136 + kt * 32 + quad * 8];
        #pragma unroll
        for (int nt = 0; nt < 4; nt++) {
            f16x8 vb = *(const f16x8*)&Vt[(nt * 16 + l15) * 136 + kt * 32 + quad * 8];
            oacc[nt] = __builtin_amdgcn_mfma_f32_16x16x32_f16(pa, vb, oacc[nt], 0, 0, 0);
        }
    }
    __builtin_amdgcn_s_setprio(0);
    __syncthreads();   // b4: all PV reads done -> overlay Pout

    _Float16* Pout = Ksh;
    #pragma unroll
    for (int nt = 0; nt < 4; nt++) {
        #pragma unroll
        for (int reg = 0; reg < 4; reg++) {
            int i = w * 16 + quad * 4 + reg;
            Pout[i * 72 + nt * 16 + l15] = (_Float16)(oacc[nt][reg] * inv_r[reg]);
        }
    }
    __syncthreads();   // b5: Pout ready

    {   // 4 threads/row, two 16B stores each: full 64B lines despite row scatter
        int row = tid >> 2, part = tid & 3;
        int y = kmeta[64 + row].y;
        _Float16* dst = attn_ws + ((size_t)hibase + y) * 64;
        f16x8 v0 = *(const f16x8*)&Pout[row * 72 + part * 8];
        f16x8 v1 = *(const f16x8*)&Pout[row * 72 + 32 + part * 8];
        *(f16x8*)(dst + part * 8) = v0;
        *(f16x8*)(dst + 32 + part * 8) = v1;
    }
}

// K4a: per (b,r) softmax-over-L stats of lse
__global__ __launch_bounds__(256) void k_rw(const float* __restrict__ lse_ws,
                                            float* __restrict__ rwmax,
                                            float* __restrict__ rwsum) {
    __shared__ float  red[256];
    __shared__ double redd[256];
    int br = blockIdx.x;
    const float* lp = lse_ws + (size_t)br * L_;
    int t = threadIdx.x;
    float m = -1e30f;
    for (int k = t; k < L_; k += 256) m = fmaxf(m, lp[k]);
    red[t] = m; __syncthreads();
    for (int s2 = 128; s2 > 0; s2 >>= 1) {
        if (t < s2) red[t] = fmaxf(red[t], red[t + s2]);
        __syncthreads();
    }
    float mm = red[0];
    double s = 0.0;
    for (int k = t; k < L_; k += 256) s += (double)expf(lp[k] - mm);
    redd[t] = s; __syncthreads();
    for (int s2 = 128; s2 > 0; s2 >>= 1) {
        if (t < s2) redd[t] += redd[t + s2];
        __syncthreads();
    }
    if (t == 0) { rwmax[br] = mm; rwsum[br] = (float)redd[0]; }
}

// K4b: vectorized combine — thread = (b,l, d-octet)
__global__ __launch_bounds__(256) void k_out(const _Float16* __restrict__ attn_ws,
                                             const float* __restrict__ lse_ws,
                                             const float* __restrict__ rwmax,
                                             const float* __restrict__ rwsum,
                                             float* __restrict__ out) {
    int gid = blockIdx.x * 256 + threadIdx.x;   // B*L*8
    int g = gid & 7;
    size_t row = (size_t)(gid >> 3);            // b*L + l
    int b = (int)(row >> 12), l = (int)(row & 4095);
    float o[8];
    #pragma unroll
    for (int k = 0; k < 8; k++) o[k] = 0.f;
    #pragma unroll
    for (int r = 0; r < 4; r++) {
        int br = b * 4 + r;
        float wgt = __expf(lse_ws[(size_t)br * L_ + l] - rwmax[br])
                  * __builtin_amdgcn_rcpf(rwsum[br]);
        f16x8 av = *(const f16x8*)&attn_ws[(((size_t)br * L_ + l) << 6) + g * 8];
        #pragma unroll
        for (int k = 0; k < 8; k++) o[k] += (float)av[k] * wgt;
    }
    float4* op = (float4*)(out + row * 64 + g * 8);
    op[0] = make_float4(o[0], o[1], o[2], o[3]);
    op[1] = make_float4(o[4], o[5], o[6], o[7]);
}

extern "C" void kernel_launch(void* const* d_in, const int* in_sizes, int n_in,
                              void* d_out, int out_size, void* d_ws, size_t ws_size,
                              hipStream_t stream) {
    const float* query = (const float*)d_in[0];
    const float* value = (const float*)d_in[1];
    const float* rm    = (const float*)d_in[2];
    char* ws = (char*)d_ws;
    int*       h_ws   = (int*)(ws + ((size_t)1 << 20));
    float*     lse_ws = (float*)(ws + ((size_t)4 << 20));
    float*     rwmax  = (float*)(ws + ((size_t)5 << 20));
    float*     rwsum  = (float*)(ws + ((size_t)5 << 20) + 256);
    _Float16*  attn_ws= (_Float16*)(ws + ((size_t)6 << 20));
    int2*      metaA  = (int2*)(ws + ((size_t)41 << 20));
    unsigned char* packB = (unsigned char*)(ws + ((size_t)43 << 20));
    float*     qscale = (float*)(ws + ((size_t)45 << 20));
    _Float16*  khf    = (_Float16*)(ws + ((size_t)53 << 20));
    _Float16*  vhf    = (_Float16*)(ws + ((size_t)61 << 20));
    float*     out    = (float*)d_out;

    hipLaunchKernelGGL(k_hash,   dim3(1024), dim3(256), 0, stream, query, value, rm,
                       h_ws, qscale, khf, vhf);
    hipLaunchKernelGGL(k_sort,   dim3(64),   dim3(256), 0, stream, h_ws, query, rm,
                       metaA, packB);
    hipLaunchKernelGGL(k_attn,   dim3(4096), dim3(256), 0, stream,
                       qscale, khf, vhf, metaA, (const unsigned int*)packB, lse_ws, attn_ws);
    hipLaunchKernelGGL(k_rw,     dim3(64),   dim3(256), 0, stream, lse_ws, rwmax, rwsum);
    hipLaunchKernelGGL(k_out,    dim3(2048), dim3(256), 0, stream,
                       attn_ws, lse_ws, rwmax, rwsum, out);
}